// Round 8
// baseline (4986.011 us; speedup 1.0000x reference)
//
#include <hip/hip_runtime.h>

// DeepAR MI355X round 9: split arrive/wait flags replace global barriers.
// r8 post-mortem: prefetch materialized (VGPR 88->128), conflicts fell 6.3x
// (4.47e8->7.1e7) — time FLAT (3585->3605). Both pipes <10%. => pace-setter
// is the lockstep sync structure. The 2 exchanges/step are irreducible
// (mu->cell0->h0 => cell1->h1/mu), but global barriers over-couple: bar1
// makes L0 wait for L1's h1prev GEMM (off-critical), bar2 makes L1 wait for
// L0's featlab+Whh0 GEMM (off-critical).
// This round: producer-group flags. f0[t] = 128 L0 WGs published h0(t)+
// mu_h0 partials; f1[t] = 128 L1 WGs published h1(t)+partials. Waits:
//   L0 step t: wait f1[t-1] (mu) -> cell0 -> arrive f0[t] -> wait f0[t]
//              -> Whh0-gemm + featlab(t+1) + reduce   [overlaps L1 critical]
//   L1 step t: wait f0[t] -> h0cur-gemm -> (wait f1[t-1], always done)
//              -> h1prev-gemm -> reduce -> cell1 -> arrive f1[t]
// Data-before-flag: s_waitcnt(0)+syncthreads before each arrival (proven
// gbar drain pattern). Parity-slot lifetimes verified through the flag DAG.
// Everything else identical to r8.
// B=128, T=160, F=512, E=64, H=1024, L=2. Output [B,T,2] fp32.

#define B_   128
#define T_   160
#define FD   512
#define E_   64
#define H_   1024
#define NT   512
#define NBLK 256
#define CH0  100                     // L0 K-chunks (K=1600: 32 feat, 4 lab, 64 h0)
#define CH1  128                     // L1 K-chunks (K=2048: 64 h0cur, 64 h1prev)
#define HT_ELEMS (64 * 4 * 512)      // per-parity h tile elems (= B_*H_)

typedef unsigned short u16;
typedef unsigned long long u64;
typedef __attribute__((ext_vector_type(8))) short bf16x8;
typedef __attribute__((ext_vector_type(16))) float f32x16;

__device__ __forceinline__ bf16x8 ld8(const u16* p) {
    return *reinterpret_cast<const bf16x8*>(p);
}
// coherent (LLC-direct) 16B load as 2x8B relaxed agent atomics — bypasses
// stale L1/L2 without needing a cache-invalidating acquire.
__device__ __forceinline__ bf16x8 ld8c(const u16* p) {
    u64* q = (u64*)p;
    union { u64 v[2]; bf16x8 f; } u_;
    u_.v[0] = __hip_atomic_load(q + 0, __ATOMIC_RELAXED, __HIP_MEMORY_SCOPE_AGENT);
    u_.v[1] = __hip_atomic_load(q + 1, __ATOMIC_RELAXED, __HIP_MEMORY_SCOPE_AGENT);
    return u_.f;
}
__device__ __forceinline__ float4 ld4f(const float* p) {
    u64* q = (u64*)p;
    union { u64 v[2]; float4 f; } u_;
    u_.v[0] = __hip_atomic_load(q + 0, __ATOMIC_RELAXED, __HIP_MEMORY_SCOPE_AGENT);
    u_.v[1] = __hip_atomic_load(q + 1, __ATOMIC_RELAXED, __HIP_MEMORY_SCOPE_AGENT);
    return u_.f;
}
__device__ __forceinline__ f32x16 mfma32(bf16x8 a, bf16x8 b, f32x16 c) {
    return __builtin_amdgcn_mfma_f32_32x32x16_bf16(a, b, c, 0, 0, 0);
}
__device__ __forceinline__ u16 f2bf(float x) {
    unsigned u = __float_as_uint(x);
    u += 0x7FFFu + ((u >> 16) & 1u);   // RNE
    return (u16)(u >> 16);
}
__device__ __forceinline__ float sigm(float x)  { return 1.f / (1.f + __expf(-x)); }
__device__ __forceinline__ float tanh_(float x) { return 1.f - 2.f / (__expf(2.f * x) + 1.f); }
__device__ __forceinline__ float softp(float x) { return x > 20.f ? x : log1pf(__expf(x)); }

__device__ __forceinline__ void st_u32(unsigned* p, unsigned v) {
    __hip_atomic_store(p, v, __ATOMIC_RELAXED, __HIP_MEMORY_SCOPE_AGENT);
}
__device__ __forceinline__ void st_f32(float* p, float v) {
    __hip_atomic_store(p, v, __ATOMIC_RELAXED, __HIP_MEMORY_SCOPE_AGENT);
}

// Split-barrier primitives over 8 spread LLC lines per flag group.
// wait: poll until sum(lines) >= target (monotone counters, 128/step).
__device__ __forceinline__ void waitf(unsigned* lines, unsigned target) {
    if (threadIdx.x == 0) {
        for (;;) {
            unsigned s = 0;
            #pragma unroll
            for (int i = 0; i < 8; ++i)
                s += __hip_atomic_load(&lines[i * 32], __ATOMIC_RELAXED,
                                       __HIP_MEMORY_SCOPE_AGENT);
            if (s >= target) break;
            __builtin_amdgcn_s_sleep(1);
        }
    }
    __atomic_signal_fence(__ATOMIC_ACQUIRE);   // compiler ordering only
    __syncthreads();
}
// arrive: all threads drain their stores to LLC, then one increment.
__device__ __forceinline__ void arrivef(unsigned* lines, int g) {
    __builtin_amdgcn_s_waitcnt(0);   // this thread's stores at LLC
    __syncthreads();                 // all threads drained
    if (threadIdx.x == 0)
        __hip_atomic_fetch_add(&lines[(g & 7) * 32], 1u,
                               __ATOMIC_RELAXED, __HIP_MEMORY_SCOPE_AGENT);
}

// ---------------- prologue kernels ----------------

__global__ void detect_mask(const unsigned* __restrict__ m, int* __restrict__ flags) {
    int i = blockIdx.x * 256 + threadIdx.x;   // exactly 5120 words (20480 bytes)
    unsigned w = m[i];
    if (w > 1u) atomicOr(&flags[0], 1);
    if (w != 0u && w != 0x3F800000u) atomicOr(&flags[1], 1);
}

// feat [B][T][512] fp32 -> fb2 [T][c=32][mblk=4][512] bf16 (MFMA A-frag tiles)
__global__ void featconv(const float* __restrict__ feat, u16* __restrict__ fb2) {
    int i = blockIdx.x * 256 + threadIdx.x;   // [0, 160*16384) float4 units
    int t = i >> 14;
    int u = i & 16383;
    int c = u >> 9;
    int r = u & 511;
    int mm = r >> 7;
    int l  = (r >> 1) & 63;
    int jj = r & 1;
    int b = mm * 32 + (l & 31);
    int k = c * 16 + (l >> 5) * 8 + jj * 4;
    float4 v = reinterpret_cast<const float4*>(feat)[((size_t)b * T_ + t) * 128 + (k >> 2)];
    ushort4 o = make_ushort4(f2bf(v.x), f2bf(v.y), f2bf(v.z), f2bf(v.w));
    reinterpret_cast<ushort4*>(fb2)[((((size_t)t * 32 + c) * 4 + mm) * 512 + l * 8 + jj * 4) >> 2] = o;
}

// ---------------- persistent kernel ----------------

struct SM0 {                       // layer-0 WGs
    u16   bw[CH0 * 512];           // 102400 B, B-frags: bw[ch*512 + lane*8 + j]
    float gtb[4224];               // 16896 B: K-reduce scratch [16][256] / gates [128][33]
    float mu_s[128];
    float uu[32], vv[32], bias[32];
    float mwv[8], swv[8];
    unsigned char msk[128];
};
struct SM1 {                       // layer-1 WGs
    u16   bw[CH1 * 512];           // 131072 B
    float gtb[4224];
    float bias[32];
    float mwv[8], swv[8];
};
union SMU { SM0 a; SM1 b; };

__global__ void __launch_bounds__(NT, 2) persist(
    const u16* __restrict__ fb2, const float* __restrict__ emb,
    const void* __restrict__ mask, const int* __restrict__ flags,
    const float* __restrict__ Wih0, const float* __restrict__ Whh0,
    const float* __restrict__ bih0, const float* __restrict__ bhh0,
    const float* __restrict__ Wih1, const float* __restrict__ Whh1,
    const float* __restrict__ bih1, const float* __restrict__ bhh1,
    const float* __restrict__ Wtgt, const float* __restrict__ btgt,
    const float* __restrict__ muw, const float* __restrict__ mubp,
    const float* __restrict__ sgw, const float* __restrict__ sgbp,
    u16* __restrict__ h0T, u16* __restrict__ h1T,
    float* __restrict__ muacc, float* __restrict__ sgacc,
    unsigned* __restrict__ actr,
    float* __restrict__ out)
{
    __shared__ SMU smu;
    const int tid  = threadIdx.x;
    const int blk  = blockIdx.x;
    const bool isL0 = blk < 128;
    const int g    = isL0 ? blk : blk - 128;   // hidden units g*8..g*8+7
    const int wv   = tid >> 6;
    const int m    = wv & 3;                   // M-tile (rows m*32..m*32+31)
    const int s    = wv >> 2;                  // K-split half
    const int lane = tid & 63;
    const int l31  = lane & 31;

    unsigned* f0l = actr;             // L0 arrival lines (stride-32 u32)
    unsigned* f1l = actr + 8 * 32;    // L1 arrival lines

    const float mub_r = mubp[0], sgb_r = sgbp[0];

    // ---- one-time init: pack weights into MFMA B-frag layout in LDS ----
    if (isL0) {
        SM0& s0 = smu.a;
        for (int i = tid; i < CH0 * 512; i += NT) {
            int ch = i >> 9, r = i & 511, l = r >> 3, jj = r & 7;
            int pc = l & 31;
            int kk = ch * 16 + (l >> 5) * 8 + jj;
            int q = pc & 3, j = pc >> 2;
            int row = q * H_ + g * 8 + j;
            float v = (kk < 576) ? Wih0[row * 576 + kk]
                                 : Whh0[(size_t)row * H_ + (kk - 576)];
            s0.bw[i] = f2bf(v);
        }
        if (tid < 32) {
            int pc = tid, q = pc & 3, j = pc >> 2;
            int row = q * H_ + g * 8 + j;
            s0.bias[pc] = bih0[row] + bhh0[row];
            float su = 0.f, sv = 0.f;
            for (int e = 0; e < 64; ++e) {       // rank-1 label vectors
                float wl = Wih0[row * 576 + 512 + e];
                su += Wtgt[e] * wl;
                sv += btgt[e] * wl;
            }
            s0.uu[pc] = su; s0.vv[pc] = sv;
        }
        if (tid < 8) {
            int h = g * 8 + tid;
            s0.mwv[tid] = muw[2 * h]; s0.swv[tid] = sgw[2 * h];
        }
    } else {
        SM1& s1 = smu.b;
        for (int i = tid; i < CH1 * 512; i += NT) {
            int ch = i >> 9, r = i & 511, l = r >> 3, jj = r & 7;
            int pc = l & 31;
            int kk = ch * 16 + (l >> 5) * 8 + jj;
            int q = pc & 3, j = pc >> 2;
            int row = q * H_ + g * 8 + j;
            float v = (kk < 1024) ? Wih1[(size_t)row * H_ + kk]
                                  : Whh1[(size_t)row * H_ + (kk - 1024)];
            s1.bw[i] = f2bf(v);
        }
        if (tid < 32) {
            int pc = tid, q = pc & 3, j = pc >> 2;
            int row = q * H_ + g * 8 + j;
            s1.bias[pc] = bih1[row] + bhh1[row];
        }
        if (tid < 8) {
            int h = g * 8 + tid;
            s1.mwv[tid] = muw[2 * h + 1]; s1.swv[tid] = sgw[2 * h + 1];
        }
    }
    const int nonbin = flags[0], nonfl = flags[1];
    __syncthreads();

    float creg0 = 0.f, creg1 = 0.f;
    f32x16 acc;
    #pragma unroll
    for (int r = 0; r < 16; ++r) acc[r] = 0.f;

    // K-split reduce: acc (both halves) -> gates in gtb[128][33]; zeroes acc.
    auto reduce_gates = [&](float* g_) {
        if (s == 1) {
            #pragma unroll
            for (int r = 0; r < 16; ++r) g_[r * 256 + m * 64 + lane] = acc[r];
        }
        __syncthreads();
        f32x16 tot;
        if (s == 0) {
            #pragma unroll
            for (int r = 0; r < 16; ++r) tot[r] = acc[r] + g_[r * 256 + m * 64 + lane];
        }
        __syncthreads();
        if (s == 0) {
            #pragma unroll
            for (int r = 0; r < 16; ++r) {
                int row = m * 32 + (r & 3) + 8 * (r >> 2) + 4 * (lane >> 5);
                g_[row * 33 + l31] = tot[r];
            }
        }
        #pragma unroll
        for (int r = 0; r < 16; ++r) acc[r] = 0.f;
    };

    // 32-chunk h-GEMM with full-depth register prefetch (r8).
    auto hgemm = [&](const u16* hp, const u16* bwb) {
        bf16x8 areg[32];
        #pragma unroll
        for (int c = 0; c < 32; ++c) {
            int ch = s * 32 + c;
            areg[c] = ld8c(hp + ((size_t)ch * 4 + m) * 512 + lane * 8);
        }
        #pragma unroll
        for (int c = 0; c < 32; ++c) {
            int ch = s * 32 + c;
            bf16x8 b = *(const bf16x8*)&bwb[ch * 512 + lane * 8];
            acc = mfma32(areg[c], b, acc);
        }
    };

    // feat+label GEMM for step t1 (chunks 0..35, s-split 18 each).
    // Labels (chunks 32..35, s==1 only) built in REGISTERS (r7).
    auto featlab = [&](int t1, bool use_mask) {
        SM0& s0 = smu.a;
        const int bq = m * 32 + l31;
        bool um = false;
        if (use_mask && s == 1) {
            int mi = bq * T_ + t1;
            um = !nonbin ? (reinterpret_cast<const int*>(mask)[mi] != 0)
               : !nonfl  ? (reinterpret_cast<const float*>(mask)[mi] != 0.f)
                         : (reinterpret_cast<const unsigned char*>(mask)[mi] != 0);
        }
        #pragma unroll 6
        for (int c = 0; c < 18; ++c) {
            int ch = s * 18 + c;
            bf16x8 a;
            if (ch < 32) {
                a = ld8(fb2 + (((size_t)t1 * 32 + ch) * 4 + m) * 512 + lane * 8);
            } else {
                const float* ep = &emb[((size_t)bq * T_ + t1) * 64
                                       + (ch - 32) * 16 + (lane >> 5) * 8];
                float4 v0 = *reinterpret_cast<const float4*>(ep);
                float4 v1 = *reinterpret_cast<const float4*>(ep + 4);
                if (um) { v0.x=v0.y=v0.z=v0.w=0.f; v1.x=v1.y=v1.z=v1.w=0.f; }
                a[0] = (short)f2bf(v0.x); a[1] = (short)f2bf(v0.y);
                a[2] = (short)f2bf(v0.z); a[3] = (short)f2bf(v0.w);
                a[4] = (short)f2bf(v1.x); a[5] = (short)f2bf(v1.y);
                a[6] = (short)f2bf(v1.z); a[7] = (short)f2bf(v1.w);
            }
            bf16x8 b = *(const bf16x8*)&s0.bw[ch * 512 + lane * 8];
            acc = mfma32(a, b, acc);
        }
    };

    // pre-loop: gates0(0) = feat(0)+lab(0) GEMM, reduced into gtb
    if (isL0) {
        featlab(0, false);
        reduce_gates(smu.a.gtb);
    }

    for (int t = 0; t < T_; ++t) {
        const int pcur = t & 1, pprev = pcur ^ 1;

        if (isL0) {
            SM0& s0 = smu.a;
            // -------- critical: mu(t-1) -> cell0(t) -> publish h0(t) --------
            if (t > 0) {
                waitf(f1l, 128u * (unsigned)t);    // h1(t-1)+partials at LLC
                if (tid < 128) {
                    float4 x = ld4f(&muacc[(pprev * 128 + tid) * 8]);
                    float4 y = ld4f(&muacc[(pprev * 128 + tid) * 8 + 4]);
                    s0.mu_s[tid] = (x.x + x.y) + (x.z + x.w) + (y.x + y.y) + (y.z + y.w) + mub_r;
                    int mi = tid * T_ + t;
                    bool um = !nonbin ? (reinterpret_cast<const int*>(mask)[mi] != 0)
                            : !nonfl  ? (reinterpret_cast<const float*>(mask)[mi] != 0.f)
                                      : (reinterpret_cast<const unsigned char*>(mask)[mi] != 0);
                    s0.msk[tid] = um ? 1 : 0;
                }
            }
            __syncthreads();
            if (t > 0 && tid == 0) {
                float4 x = ld4f(&sgacc[(pprev * 128 + g) * 8]);
                float4 y = ld4f(&sgacc[(pprev * 128 + g) * 8 + 4]);
                float sg = (x.x + x.y) + (x.z + x.w) + (y.x + y.y) + (y.z + y.w) + sgb_r;
                out[((size_t)g * T_ + (t - 1)) * 2 + 0] = s0.mu_s[g];
                out[((size_t)g * T_ + (t - 1)) * 2 + 1] = softp(sg);
            }
            // cell0 + h0 publish (fragment-tiled, full-line) + partial atomics
            u16* hw = h0T + (size_t)pcur * HT_ELEMS;
            const int c_ = g >> 1, half = g & 1;
            #pragma unroll
            for (int p = 0; p < 2; ++p) {
                int id = tid + p * NT;
                int b = id >> 3, j = id & 7;
                float gi = s0.gtb[b * 33 + 4 * j + 0] + s0.bias[4 * j + 0];
                float gf = s0.gtb[b * 33 + 4 * j + 1] + s0.bias[4 * j + 1];
                float gg = s0.gtb[b * 33 + 4 * j + 2] + s0.bias[4 * j + 2];
                float go = s0.gtb[b * 33 + 4 * j + 3] + s0.bias[4 * j + 3];
                if (t > 0 && s0.msk[b]) {       // rank-1 mu-label term (fp32 exact)
                    float mu = s0.mu_s[b];
                    gi += mu * s0.uu[4 * j + 0] + s0.vv[4 * j + 0];
                    gf += mu * s0.uu[4 * j + 1] + s0.vv[4 * j + 1];
                    gg += mu * s0.uu[4 * j + 2] + s0.vv[4 * j + 2];
                    go += mu * s0.uu[4 * j + 3] + s0.vv[4 * j + 3];
                }
                float cold = (p == 0) ? creg0 : creg1;
                float cn = sigm(gf) * cold + sigm(gi) * tanh_(gg);
                float hn = sigm(go) * tanh_(cn);
                if (p == 0) creg0 = cn; else creg1 = cn;
                unsigned hv = f2bf(hn);
                unsigned other = (unsigned)__shfl_xor((int)hv, 1);
                if ((j & 1) == 0) {
                    int l = half * 32 + (b & 31), mb = b >> 5;
                    st_u32(reinterpret_cast<unsigned*>(hw + ((size_t)(c_ * 4 + mb) * 512 + l * 8 + j)),
                           hv | (other << 16));
                }
                float pmu = hn * s0.mwv[j], psg = hn * s0.swv[j];
                pmu += __shfl_xor(pmu, 1); pmu += __shfl_xor(pmu, 2); pmu += __shfl_xor(pmu, 4);
                psg += __shfl_xor(psg, 1); psg += __shfl_xor(psg, 2); psg += __shfl_xor(psg, 4);
                if (j == 0) {
                    atomicAdd(&muacc[(pcur * 128 + b) * 8 + (g & 7)], pmu);
                    atomicAdd(&sgacc[(pcur * 128 + b) * 8 + (g & 7)], psg);
                }
            }
            arrivef(f0l, g);                      // h0(t)+partials published

            // -------- off-critical: gates0(t+1), overlaps L1's chain --------
            if (t + 1 < T_) {
                waitf(f0l, 128u * (unsigned)(t + 1));   // all h0(t) slices
                hgemm(h0T + (size_t)pcur * HT_ELEMS, &s0.bw[36 * 512]);
                featlab(t + 1, true);
                reduce_gates(s0.gtb);
            }
        } else {
            SM1& s1 = smu.b;
            // -------- critical: h0(t) -> gates1 -> cell1 -> publish h1(t) ---
            waitf(f0l, 128u * (unsigned)(t + 1));       // h0(t) at LLC
            if (t > 0 && tid < 8) {     // zero consumed parity slots:
                // safe: f0[t]=128 => all L0 finished reading mu(t-1); next
                // writers (step t+1) are gated behind f1[t] > this arrive.
                st_f32(&muacc[(pprev * 128 + g) * 8 + tid], 0.f);
                st_f32(&sgacc[(pprev * 128 + g) * 8 + tid], 0.f);
            }
            hgemm(h0T + (size_t)pcur * HT_ELEMS, &s1.bw[0]);        // h0cur
            if (t > 0) {
                waitf(f1l, 128u * (unsigned)t);   // h1(t-1) (already complete:
                                                  // f0[t] implies f1[t-1])
                hgemm(h1T + (size_t)pprev * HT_ELEMS, &s1.bw[64 * 512]);
            }
            reduce_gates(s1.gtb);
            __syncthreads();
            // cell1 + h1 publish + partial atomics
            u16* hw = h1T + (size_t)pcur * HT_ELEMS;
            const int c_ = g >> 1, half = g & 1;
            #pragma unroll
            for (int p = 0; p < 2; ++p) {
                int id = tid + p * NT;
                int b = id >> 3, j = id & 7;
                float gi = s1.gtb[b * 33 + 4 * j + 0] + s1.bias[4 * j + 0];
                float gf = s1.gtb[b * 33 + 4 * j + 1] + s1.bias[4 * j + 1];
                float gg = s1.gtb[b * 33 + 4 * j + 2] + s1.bias[4 * j + 2];
                float go = s1.gtb[b * 33 + 4 * j + 3] + s1.bias[4 * j + 3];
                float cold = (p == 0) ? creg0 : creg1;
                float cn = sigm(gf) * cold + sigm(gi) * tanh_(gg);
                float hn = sigm(go) * tanh_(cn);
                if (p == 0) creg0 = cn; else creg1 = cn;
                unsigned hv = f2bf(hn);
                unsigned other = (unsigned)__shfl_xor((int)hv, 1);
                if ((j & 1) == 0) {
                    int l = half * 32 + (b & 31), mb = b >> 5;
                    st_u32(reinterpret_cast<unsigned*>(hw + ((size_t)(c_ * 4 + mb) * 512 + l * 8 + j)),
                           hv | (other << 16));
                }
                float pmu = hn * s1.mwv[j], psg = hn * s1.swv[j];
                pmu += __shfl_xor(pmu, 1); pmu += __shfl_xor(pmu, 2); pmu += __shfl_xor(pmu, 4);
                psg += __shfl_xor(psg, 1); psg += __shfl_xor(psg, 2); psg += __shfl_xor(psg, 4);
                if (j == 0) {
                    atomicAdd(&muacc[(pcur * 128 + b) * 8 + (g & 7)], pmu);
                    atomicAdd(&sgacc[(pcur * 128 + b) * 8 + (g & 7)], psg);
                }
            }
            arrivef(f1l, g);                      // h1(t)+partials published
        }
    }

    // ---- final output t = T_-1 (parity 1) ----
    if (isL0) {
        waitf(f1l, 128u * (unsigned)T_);          // h1(T-1) partials at LLC
        if (tid == 0) {
            float4 x = ld4f(&muacc[(1 * 128 + g) * 8]);
            float4 y = ld4f(&muacc[(1 * 128 + g) * 8 + 4]);
            float mu = (x.x + x.y) + (x.z + x.w) + (y.x + y.y) + (y.z + y.w) + mub_r;
            float4 z = ld4f(&sgacc[(1 * 128 + g) * 8]);
            float4 u2 = ld4f(&sgacc[(1 * 128 + g) * 8 + 4]);
            float sg = (z.x + z.y) + (z.z + z.w) + (u2.x + u2.y) + (u2.z + u2.w) + sgb_r;
            out[((size_t)g * T_ + (T_ - 1)) * 2 + 0] = mu;
            out[((size_t)g * T_ + (T_ - 1)) * 2 + 1] = softp(sg);
        }
    }
}

// ---------------- host ----------------

extern "C" void kernel_launch(void* const* d_in, const int* in_sizes, int n_in,
                              void* d_out, int out_size, void* d_ws, size_t ws_size,
                              hipStream_t stream) {
    const float* feat = (const float*)d_in[0];
    const float* emb  = (const float*)d_in[1];
    const void*  mask = d_in[2];
    const float* Wih0 = (const float*)d_in[3];
    const float* Whh0 = (const float*)d_in[4];
    const float* bih0 = (const float*)d_in[5];
    const float* bhh0 = (const float*)d_in[6];
    const float* Wih1 = (const float*)d_in[7];
    const float* Whh1 = (const float*)d_in[8];
    const float* bih1 = (const float*)d_in[9];
    const float* bhh1 = (const float*)d_in[10];
    const float* Wtgt = (const float*)d_in[11];
    const float* btgt = (const float*)d_in[12];
    const float* muw  = (const float*)d_in[13];
    const float* mub  = (const float*)d_in[14];
    const float* sgw  = (const float*)d_in[15];
    const float* sgb  = (const float*)d_in[16];
    float* out = (float*)d_out;
    char* ws = (char*)d_ws;
    (void)in_sizes; (void)n_in; (void)out_size; (void)ws_size;

    size_t off = 0;
    auto alloc = [&](size_t bytes) {
        size_t o = off;
        off = (off + bytes + 255) & ~(size_t)255;
        return o;
    };
    size_t o_flags = alloc(256);
    size_t o_actr  = alloc(16 * 32 * 4);     // f0 lines [0..7], f1 lines [8..15]
    size_t o_muacc = alloc((size_t)2 * 128 * 8 * 4);
    size_t o_sgacc = alloc((size_t)2 * 128 * 8 * 4);
    size_t zero_end = off;
    size_t o_h0    = alloc((size_t)2 * HT_ELEMS * 2);
    size_t o_h1    = alloc((size_t)2 * HT_ELEMS * 2);
    size_t o_fb2   = alloc((size_t)T_ * 32 * 4 * 512 * 2);

    int*      flags = (int*)(ws + o_flags);
    unsigned* actr  = (unsigned*)(ws + o_actr);
    float*    muacc = (float*)(ws + o_muacc);
    float*    sgacc = (float*)(ws + o_sgacc);
    u16*      h0    = (u16*)(ws + o_h0);
    u16*      h1    = (u16*)(ws + o_h1);
    u16*      fb2   = (u16*)(ws + o_fb2);

    hipMemsetAsync(ws, 0, zero_end, stream);
    detect_mask<<<20, 256, 0, stream>>>((const unsigned*)mask, flags);
    featconv<<<10240, 256, 0, stream>>>(feat, fb2);

    persist<<<NBLK, NT, 0, stream>>>(
        fb2, emb, mask, flags,
        Wih0, Whh0, bih0, bhh0,
        Wih1, Whh1, bih1, bhh1,
        Wtgt, btgt, muw, mub, sgw, sgb,
        h0, h1, muacc, sgacc, actr, out);
}

// Round 9
// 3494.971 us; speedup vs baseline: 1.4266x; 1.4266x over previous
//
#include <hip/hip_runtime.h>

// DeepAR MI355X round 10: split flags done right (aggregator + release word).
// r9 post-mortem (+38% regression): all-256-WG direct polling of 8 spread
// lines = poll storm on LLC (vs r4-r8's 1-word release polling) slowed every
// phase uniformly (MfmaUtil 7->5, VALUBusy 8.4->5.9). Also h1prev GEMM was
// misplaced INSIDE L1's critical section.
// This round keeps decoupled producer-group flags but restores cheap polls:
//   arrivals: 8 spread lines/group, FAA after s_waitcnt(0)+syncthreads drain
//   releases: blk0 aggregates f1 lines -> rel1 (it's the earliest f1
//             consumer); blk128 aggregates f0 lines -> rel0. Everyone else
//             polls ONE release word (r6-proven traffic level).
// Schedule per step t:
//   L0: [wait rel1>=t; read mu] -> cell0 -> arrive f0 ->
//       [wait rel0>=t+1; Whh0-gemm + featlab(t+1) + reduce]  (off-critical,
//       overlaps L1's critical chain)
//   L1: [wait rel1>=t; h1prev-gemm]  (overlaps L0's cell0) ->
//       wait rel0>=t+1 -> h0cur-gemm -> reduce -> cell1 -> arrive f1
// Deadlock-freedom: aggregators poll raw lines only; dependency graph is a
// DAG (traced in session notes). Data-before-flag: proven drain pattern.
// Everything else identical to r8/r9 (prefetch hgemm, reg labels, inv-free
// coherence).
// B=128, T=160, F=512, E=64, H=1024, L=2. Output [B,T,2] fp32.

#define B_   128
#define T_   160
#define FD   512
#define E_   64
#define H_   1024
#define NT   512
#define NBLK 256
#define CH0  100                     // L0 K-chunks (K=1600: 32 feat, 4 lab, 64 h0)
#define CH1  128                     // L1 K-chunks (K=2048: 64 h0cur, 64 h1prev)
#define HT_ELEMS (64 * 4 * 512)      // per-parity h tile elems (= B_*H_)

typedef unsigned short u16;
typedef unsigned long long u64;
typedef __attribute__((ext_vector_type(8))) short bf16x8;
typedef __attribute__((ext_vector_type(16))) float f32x16;

__device__ __forceinline__ bf16x8 ld8(const u16* p) {
    return *reinterpret_cast<const bf16x8*>(p);
}
// coherent (LLC-direct) 16B load as 2x8B relaxed agent atomics — bypasses
// stale L1/L2 without needing a cache-invalidating acquire.
__device__ __forceinline__ bf16x8 ld8c(const u16* p) {
    u64* q = (u64*)p;
    union { u64 v[2]; bf16x8 f; } u_;
    u_.v[0] = __hip_atomic_load(q + 0, __ATOMIC_RELAXED, __HIP_MEMORY_SCOPE_AGENT);
    u_.v[1] = __hip_atomic_load(q + 1, __ATOMIC_RELAXED, __HIP_MEMORY_SCOPE_AGENT);
    return u_.f;
}
__device__ __forceinline__ float4 ld4f(const float* p) {
    u64* q = (u64*)p;
    union { u64 v[2]; float4 f; } u_;
    u_.v[0] = __hip_atomic_load(q + 0, __ATOMIC_RELAXED, __HIP_MEMORY_SCOPE_AGENT);
    u_.v[1] = __hip_atomic_load(q + 1, __ATOMIC_RELAXED, __HIP_MEMORY_SCOPE_AGENT);
    return u_.f;
}
__device__ __forceinline__ f32x16 mfma32(bf16x8 a, bf16x8 b, f32x16 c) {
    return __builtin_amdgcn_mfma_f32_32x32x16_bf16(a, b, c, 0, 0, 0);
}
__device__ __forceinline__ u16 f2bf(float x) {
    unsigned u = __float_as_uint(x);
    u += 0x7FFFu + ((u >> 16) & 1u);   // RNE
    return (u16)(u >> 16);
}
__device__ __forceinline__ float sigm(float x)  { return 1.f / (1.f + __expf(-x)); }
__device__ __forceinline__ float tanh_(float x) { return 1.f - 2.f / (__expf(2.f * x) + 1.f); }
__device__ __forceinline__ float softp(float x) { return x > 20.f ? x : log1pf(__expf(x)); }

__device__ __forceinline__ void st_u32(unsigned* p, unsigned v) {
    __hip_atomic_store(p, v, __ATOMIC_RELAXED, __HIP_MEMORY_SCOPE_AGENT);
}
__device__ __forceinline__ void st_f32(float* p, float v) {
    __hip_atomic_store(p, v, __ATOMIC_RELAXED, __HIP_MEMORY_SCOPE_AGENT);
}

// ---- split-barrier primitives (aggregator + release-word topology) ----

// waiter: poll a single release word until >= tgt (r6-proven load level)
__device__ __forceinline__ void wait_rel(unsigned* rel, unsigned tgt) {
    if (threadIdx.x == 0)
        while (__hip_atomic_load(rel, __ATOMIC_RELAXED, __HIP_MEMORY_SCOPE_AGENT) < tgt)
            __builtin_amdgcn_s_sleep(2);
    __atomic_signal_fence(__ATOMIC_ACQUIRE);   // compiler ordering only
    __syncthreads();
}
// aggregator: poll 8 spread lines until count >= cnt, then publish relval
__device__ __forceinline__ void agg_publish(unsigned* lines, unsigned cnt,
                                            unsigned* rel, unsigned relval) {
    if (threadIdx.x == 0) {
        for (;;) {
            unsigned ssum = 0;
            #pragma unroll
            for (int i = 0; i < 8; ++i)
                ssum += __hip_atomic_load(&lines[i * 32], __ATOMIC_RELAXED,
                                          __HIP_MEMORY_SCOPE_AGENT);
            if (ssum >= cnt) break;
            __builtin_amdgcn_s_sleep(2);
        }
        __hip_atomic_store(rel, relval, __ATOMIC_RELAXED, __HIP_MEMORY_SCOPE_AGENT);
    }
    __atomic_signal_fence(__ATOMIC_ACQUIRE);
    __syncthreads();
}
// arrive: all threads drain stores to LLC, then one FAA on group's line.
__device__ __forceinline__ void arrivef(unsigned* lines, int g) {
    __builtin_amdgcn_s_waitcnt(0);   // this wave's stores/atomics at LLC
    __syncthreads();                 // all waves drained
    if (threadIdx.x == 0)
        __hip_atomic_fetch_add(&lines[(g & 7) * 32], 1u,
                               __ATOMIC_RELAXED, __HIP_MEMORY_SCOPE_AGENT);
}

// ---------------- prologue kernels ----------------

__global__ void detect_mask(const unsigned* __restrict__ m, int* __restrict__ flags) {
    int i = blockIdx.x * 256 + threadIdx.x;   // exactly 5120 words (20480 bytes)
    unsigned w = m[i];
    if (w > 1u) atomicOr(&flags[0], 1);
    if (w != 0u && w != 0x3F800000u) atomicOr(&flags[1], 1);
}

// feat [B][T][512] fp32 -> fb2 [T][c=32][mblk=4][512] bf16 (MFMA A-frag tiles)
__global__ void featconv(const float* __restrict__ feat, u16* __restrict__ fb2) {
    int i = blockIdx.x * 256 + threadIdx.x;   // [0, 160*16384) float4 units
    int t = i >> 14;
    int u = i & 16383;
    int c = u >> 9;
    int r = u & 511;
    int mm = r >> 7;
    int l  = (r >> 1) & 63;
    int jj = r & 1;
    int b = mm * 32 + (l & 31);
    int k = c * 16 + (l >> 5) * 8 + jj * 4;
    float4 v = reinterpret_cast<const float4*>(feat)[((size_t)b * T_ + t) * 128 + (k >> 2)];
    ushort4 o = make_ushort4(f2bf(v.x), f2bf(v.y), f2bf(v.z), f2bf(v.w));
    reinterpret_cast<ushort4*>(fb2)[((((size_t)t * 32 + c) * 4 + mm) * 512 + l * 8 + jj * 4) >> 2] = o;
}

// ---------------- persistent kernel ----------------

struct SM0 {                       // layer-0 WGs
    u16   bw[CH0 * 512];           // 102400 B, B-frags: bw[ch*512 + lane*8 + j]
    float gtb[4224];               // 16896 B: K-reduce scratch [16][256] / gates [128][33]
    float mu_s[128];
    float uu[32], vv[32], bias[32];
    float mwv[8], swv[8];
    unsigned char msk[128];
};
struct SM1 {                       // layer-1 WGs
    u16   bw[CH1 * 512];           // 131072 B
    float gtb[4224];
    float bias[32];
    float mwv[8], swv[8];
};
union SMU { SM0 a; SM1 b; };

__global__ void __launch_bounds__(NT, 2) persist(
    const u16* __restrict__ fb2, const float* __restrict__ emb,
    const void* __restrict__ mask, const int* __restrict__ flags,
    const float* __restrict__ Wih0, const float* __restrict__ Whh0,
    const float* __restrict__ bih0, const float* __restrict__ bhh0,
    const float* __restrict__ Wih1, const float* __restrict__ Whh1,
    const float* __restrict__ bih1, const float* __restrict__ bhh1,
    const float* __restrict__ Wtgt, const float* __restrict__ btgt,
    const float* __restrict__ muw, const float* __restrict__ mubp,
    const float* __restrict__ sgw, const float* __restrict__ sgbp,
    u16* __restrict__ h0T, u16* __restrict__ h1T,
    float* __restrict__ muacc, float* __restrict__ sgacc,
    unsigned* __restrict__ actr,
    float* __restrict__ out)
{
    __shared__ SMU smu;
    const int tid  = threadIdx.x;
    const int blk  = blockIdx.x;
    const bool isL0 = blk < 128;
    const int g    = isL0 ? blk : blk - 128;   // hidden units g*8..g*8+7
    const int wv   = tid >> 6;
    const int m    = wv & 3;                   // M-tile (rows m*32..m*32+31)
    const int s    = wv >> 2;                  // K-split half
    const int lane = tid & 63;
    const int l31  = lane & 31;

    unsigned* f0l  = actr;             // L0 arrival lines (stride-32 u32)
    unsigned* f1l  = actr + 8 * 32;    // L1 arrival lines
    unsigned* rel0 = actr + 16 * 32;   // published by blk128 (f0 aggregator)
    unsigned* rel1 = actr + 16 * 32 + 32;  // published by blk0 (f1 aggregator)

    const float mub_r = mubp[0], sgb_r = sgbp[0];

    // ---- one-time init: pack weights into MFMA B-frag layout in LDS ----
    if (isL0) {
        SM0& s0 = smu.a;
        for (int i = tid; i < CH0 * 512; i += NT) {
            int ch = i >> 9, r = i & 511, l = r >> 3, jj = r & 7;
            int pc = l & 31;
            int kk = ch * 16 + (l >> 5) * 8 + jj;
            int q = pc & 3, j = pc >> 2;
            int row = q * H_ + g * 8 + j;
            float v = (kk < 576) ? Wih0[row * 576 + kk]
                                 : Whh0[(size_t)row * H_ + (kk - 576)];
            s0.bw[i] = f2bf(v);
        }
        if (tid < 32) {
            int pc = tid, q = pc & 3, j = pc >> 2;
            int row = q * H_ + g * 8 + j;
            s0.bias[pc] = bih0[row] + bhh0[row];
            float su = 0.f, sv = 0.f;
            for (int e = 0; e < 64; ++e) {       // rank-1 label vectors
                float wl = Wih0[row * 576 + 512 + e];
                su += Wtgt[e] * wl;
                sv += btgt[e] * wl;
            }
            s0.uu[pc] = su; s0.vv[pc] = sv;
        }
        if (tid < 8) {
            int h = g * 8 + tid;
            s0.mwv[tid] = muw[2 * h]; s0.swv[tid] = sgw[2 * h];
        }
    } else {
        SM1& s1 = smu.b;
        for (int i = tid; i < CH1 * 512; i += NT) {
            int ch = i >> 9, r = i & 511, l = r >> 3, jj = r & 7;
            int pc = l & 31;
            int kk = ch * 16 + (l >> 5) * 8 + jj;
            int q = pc & 3, j = pc >> 2;
            int row = q * H_ + g * 8 + j;
            float v = (kk < 1024) ? Wih1[(size_t)row * H_ + kk]
                                  : Whh1[(size_t)row * H_ + (kk - 1024)];
            s1.bw[i] = f2bf(v);
        }
        if (tid < 32) {
            int pc = tid, q = pc & 3, j = pc >> 2;
            int row = q * H_ + g * 8 + j;
            s1.bias[pc] = bih1[row] + bhh1[row];
        }
        if (tid < 8) {
            int h = g * 8 + tid;
            s1.mwv[tid] = muw[2 * h + 1]; s1.swv[tid] = sgw[2 * h + 1];
        }
    }
    const int nonbin = flags[0], nonfl = flags[1];
    __syncthreads();

    float creg0 = 0.f, creg1 = 0.f;
    f32x16 acc;
    #pragma unroll
    for (int r = 0; r < 16; ++r) acc[r] = 0.f;

    // K-split reduce: acc (both halves) -> gates in gtb[128][33]; zeroes acc.
    auto reduce_gates = [&](float* g_) {
        if (s == 1) {
            #pragma unroll
            for (int r = 0; r < 16; ++r) g_[r * 256 + m * 64 + lane] = acc[r];
        }
        __syncthreads();
        f32x16 tot;
        if (s == 0) {
            #pragma unroll
            for (int r = 0; r < 16; ++r) tot[r] = acc[r] + g_[r * 256 + m * 64 + lane];
        }
        __syncthreads();
        if (s == 0) {
            #pragma unroll
            for (int r = 0; r < 16; ++r) {
                int row = m * 32 + (r & 3) + 8 * (r >> 2) + 4 * (lane >> 5);
                g_[row * 33 + l31] = tot[r];
            }
        }
        #pragma unroll
        for (int r = 0; r < 16; ++r) acc[r] = 0.f;
    };

    // 32-chunk h-GEMM with full-depth register prefetch (r8).
    auto hgemm = [&](const u16* hp, const u16* bwb) {
        bf16x8 areg[32];
        #pragma unroll
        for (int c = 0; c < 32; ++c) {
            int ch = s * 32 + c;
            areg[c] = ld8c(hp + ((size_t)ch * 4 + m) * 512 + lane * 8);
        }
        #pragma unroll
        for (int c = 0; c < 32; ++c) {
            int ch = s * 32 + c;
            bf16x8 b = *(const bf16x8*)&bwb[ch * 512 + lane * 8];
            acc = mfma32(areg[c], b, acc);
        }
    };

    // feat+label GEMM for step t1 (chunks 0..35, s-split 18 each).
    // Labels (chunks 32..35, s==1 only) built in REGISTERS (r7).
    auto featlab = [&](int t1, bool use_mask) {
        SM0& s0 = smu.a;
        const int bq = m * 32 + l31;
        bool um = false;
        if (use_mask && s == 1) {
            int mi = bq * T_ + t1;
            um = !nonbin ? (reinterpret_cast<const int*>(mask)[mi] != 0)
               : !nonfl  ? (reinterpret_cast<const float*>(mask)[mi] != 0.f)
                         : (reinterpret_cast<const unsigned char*>(mask)[mi] != 0);
        }
        #pragma unroll 6
        for (int c = 0; c < 18; ++c) {
            int ch = s * 18 + c;
            bf16x8 a;
            if (ch < 32) {
                a = ld8(fb2 + (((size_t)t1 * 32 + ch) * 4 + m) * 512 + lane * 8);
            } else {
                const float* ep = &emb[((size_t)bq * T_ + t1) * 64
                                       + (ch - 32) * 16 + (lane >> 5) * 8];
                float4 v0 = *reinterpret_cast<const float4*>(ep);
                float4 v1 = *reinterpret_cast<const float4*>(ep + 4);
                if (um) { v0.x=v0.y=v0.z=v0.w=0.f; v1.x=v1.y=v1.z=v1.w=0.f; }
                a[0] = (short)f2bf(v0.x); a[1] = (short)f2bf(v0.y);
                a[2] = (short)f2bf(v0.z); a[3] = (short)f2bf(v0.w);
                a[4] = (short)f2bf(v1.x); a[5] = (short)f2bf(v1.y);
                a[6] = (short)f2bf(v1.z); a[7] = (short)f2bf(v1.w);
            }
            bf16x8 b = *(const bf16x8*)&s0.bw[ch * 512 + lane * 8];
            acc = mfma32(a, b, acc);
        }
    };

    // pre-loop: gates0(0) = feat(0)+lab(0) GEMM, reduced into gtb
    if (isL0) {
        featlab(0, false);
        reduce_gates(smu.a.gtb);
    }

    for (int t = 0; t < T_; ++t) {
        const int pcur = t & 1, pprev = pcur ^ 1;

        if (isL0) {
            SM0& s0 = smu.a;
            // -------- critical: mu(t-1) -> cell0(t) -> publish h0(t) --------
            if (t > 0) {
                if (blk == 0) agg_publish(f1l, 128u * (unsigned)t, rel1, (unsigned)t);
                else          wait_rel(rel1, (unsigned)t);
                if (tid < 128) {
                    float4 x = ld4f(&muacc[(pprev * 128 + tid) * 8]);
                    float4 y = ld4f(&muacc[(pprev * 128 + tid) * 8 + 4]);
                    s0.mu_s[tid] = (x.x + x.y) + (x.z + x.w) + (y.x + y.y) + (y.z + y.w) + mub_r;
                    int mi = tid * T_ + t;
                    bool um = !nonbin ? (reinterpret_cast<const int*>(mask)[mi] != 0)
                            : !nonfl  ? (reinterpret_cast<const float*>(mask)[mi] != 0.f)
                                      : (reinterpret_cast<const unsigned char*>(mask)[mi] != 0);
                    s0.msk[tid] = um ? 1 : 0;
                }
            }
            __syncthreads();
            if (t > 0 && tid == 0) {
                float4 x = ld4f(&sgacc[(pprev * 128 + g) * 8]);
                float4 y = ld4f(&sgacc[(pprev * 128 + g) * 8 + 4]);
                float sg = (x.x + x.y) + (x.z + x.w) + (y.x + y.y) + (y.z + y.w) + sgb_r;
                out[((size_t)g * T_ + (t - 1)) * 2 + 0] = s0.mu_s[g];
                out[((size_t)g * T_ + (t - 1)) * 2 + 1] = softp(sg);
            }
            // cell0 + h0 publish (fragment-tiled, full-line) + partial atomics
            u16* hw = h0T + (size_t)pcur * HT_ELEMS;
            const int c_ = g >> 1, half = g & 1;
            #pragma unroll
            for (int p = 0; p < 2; ++p) {
                int id = tid + p * NT;
                int b = id >> 3, j = id & 7;
                float gi = s0.gtb[b * 33 + 4 * j + 0] + s0.bias[4 * j + 0];
                float gf = s0.gtb[b * 33 + 4 * j + 1] + s0.bias[4 * j + 1];
                float gg = s0.gtb[b * 33 + 4 * j + 2] + s0.bias[4 * j + 2];
                float go = s0.gtb[b * 33 + 4 * j + 3] + s0.bias[4 * j + 3];
                if (t > 0 && s0.msk[b]) {       // rank-1 mu-label term (fp32 exact)
                    float mu = s0.mu_s[b];
                    gi += mu * s0.uu[4 * j + 0] + s0.vv[4 * j + 0];
                    gf += mu * s0.uu[4 * j + 1] + s0.vv[4 * j + 1];
                    gg += mu * s0.uu[4 * j + 2] + s0.vv[4 * j + 2];
                    go += mu * s0.uu[4 * j + 3] + s0.vv[4 * j + 3];
                }
                float cold = (p == 0) ? creg0 : creg1;
                float cn = sigm(gf) * cold + sigm(gi) * tanh_(gg);
                float hn = sigm(go) * tanh_(cn);
                if (p == 0) creg0 = cn; else creg1 = cn;
                unsigned hv = f2bf(hn);
                unsigned other = (unsigned)__shfl_xor((int)hv, 1);
                if ((j & 1) == 0) {
                    int l = half * 32 + (b & 31), mb = b >> 5;
                    st_u32(reinterpret_cast<unsigned*>(hw + ((size_t)(c_ * 4 + mb) * 512 + l * 8 + j)),
                           hv | (other << 16));
                }
                float pmu = hn * s0.mwv[j], psg = hn * s0.swv[j];
                pmu += __shfl_xor(pmu, 1); pmu += __shfl_xor(pmu, 2); pmu += __shfl_xor(pmu, 4);
                psg += __shfl_xor(psg, 1); psg += __shfl_xor(psg, 2); psg += __shfl_xor(psg, 4);
                if (j == 0) {
                    atomicAdd(&muacc[(pcur * 128 + b) * 8 + (g & 7)], pmu);
                    atomicAdd(&sgacc[(pcur * 128 + b) * 8 + (g & 7)], psg);
                }
            }
            arrivef(f0l, g);                      // h0(t)+partials published

            // -------- off-critical: gates0(t+1), overlaps L1's chain --------
            if (t + 1 < T_) {
                wait_rel(rel0, (unsigned)(t + 1));      // all h0(t) slices
                hgemm(h0T + (size_t)pcur * HT_ELEMS, &s0.bw[36 * 512]);
                featlab(t + 1, true);
                reduce_gates(s0.gtb);
            }
        } else {
            SM1& s1 = smu.b;
            // -------- h1prev GEMM first: overlaps L0's cell0 --------
            if (t > 0) {
                wait_rel(rel1, (unsigned)t);      // own group, nearly free
                hgemm(h1T + (size_t)pprev * HT_ELEMS, &s1.bw[64 * 512]);
            }
            // -------- critical: h0(t) -> gates1 -> cell1 -> publish ---------
            if (blk == 128) agg_publish(f0l, 128u * (unsigned)(t + 1), rel0, (unsigned)(t + 1));
            else            wait_rel(rel0, (unsigned)(t + 1));
            if (t > 0 && tid < 8) {     // zero consumed parity slots:
                // safe: rel0>=t+1 => all L0 read mu(t-1); step-t+1 writers
                // are gated behind f1[t] which is after this WG's arrive.
                st_f32(&muacc[(pprev * 128 + g) * 8 + tid], 0.f);
                st_f32(&sgacc[(pprev * 128 + g) * 8 + tid], 0.f);
            }
            hgemm(h0T + (size_t)pcur * HT_ELEMS, &s1.bw[0]);        // h0cur
            reduce_gates(s1.gtb);
            __syncthreads();
            // cell1 + h1 publish + partial atomics
            u16* hw = h1T + (size_t)pcur * HT_ELEMS;
            const int c_ = g >> 1, half = g & 1;
            #pragma unroll
            for (int p = 0; p < 2; ++p) {
                int id = tid + p * NT;
                int b = id >> 3, j = id & 7;
                float gi = s1.gtb[b * 33 + 4 * j + 0] + s1.bias[4 * j + 0];
                float gf = s1.gtb[b * 33 + 4 * j + 1] + s1.bias[4 * j + 1];
                float gg = s1.gtb[b * 33 + 4 * j + 2] + s1.bias[4 * j + 2];
                float go = s1.gtb[b * 33 + 4 * j + 3] + s1.bias[4 * j + 3];
                float cold = (p == 0) ? creg0 : creg1;
                float cn = sigm(gf) * cold + sigm(gi) * tanh_(gg);
                float hn = sigm(go) * tanh_(cn);
                if (p == 0) creg0 = cn; else creg1 = cn;
                unsigned hv = f2bf(hn);
                unsigned other = (unsigned)__shfl_xor((int)hv, 1);
                if ((j & 1) == 0) {
                    int l = half * 32 + (b & 31), mb = b >> 5;
                    st_u32(reinterpret_cast<unsigned*>(hw + ((size_t)(c_ * 4 + mb) * 512 + l * 8 + j)),
                           hv | (other << 16));
                }
                float pmu = hn * s1.mwv[j], psg = hn * s1.swv[j];
                pmu += __shfl_xor(pmu, 1); pmu += __shfl_xor(pmu, 2); pmu += __shfl_xor(pmu, 4);
                psg += __shfl_xor(psg, 1); psg += __shfl_xor(psg, 2); psg += __shfl_xor(psg, 4);
                if (j == 0) {
                    atomicAdd(&muacc[(pcur * 128 + b) * 8 + (g & 7)], pmu);
                    atomicAdd(&sgacc[(pcur * 128 + b) * 8 + (g & 7)], psg);
                }
            }
            arrivef(f1l, g);                      // h1(t)+partials published
        }
    }

    // ---- final output t = T_-1 (parity 1) ----
    if (isL0) {
        if (blk == 0) agg_publish(f1l, 128u * (unsigned)T_, rel1, (unsigned)T_);
        else          wait_rel(rel1, (unsigned)T_);
        if (tid == 0) {
            float4 x = ld4f(&muacc[(1 * 128 + g) * 8]);
            float4 y = ld4f(&muacc[(1 * 128 + g) * 8 + 4]);
            float mu = (x.x + x.y) + (x.z + x.w) + (y.x + y.y) + (y.z + y.w) + mub_r;
            float4 z = ld4f(&sgacc[(1 * 128 + g) * 8]);
            float4 u2 = ld4f(&sgacc[(1 * 128 + g) * 8 + 4]);
            float sg = (z.x + z.y) + (z.z + z.w) + (u2.x + u2.y) + (u2.z + u2.w) + sgb_r;
            out[((size_t)g * T_ + (T_ - 1)) * 2 + 0] = mu;
            out[((size_t)g * T_ + (T_ - 1)) * 2 + 1] = softp(sg);
        }
    }
}

// ---------------- host ----------------

extern "C" void kernel_launch(void* const* d_in, const int* in_sizes, int n_in,
                              void* d_out, int out_size, void* d_ws, size_t ws_size,
                              hipStream_t stream) {
    const float* feat = (const float*)d_in[0];
    const float* emb  = (const float*)d_in[1];
    const void*  mask = d_in[2];
    const float* Wih0 = (const float*)d_in[3];
    const float* Whh0 = (const float*)d_in[4];
    const float* bih0 = (const float*)d_in[5];
    const float* bhh0 = (const float*)d_in[6];
    const float* Wih1 = (const float*)d_in[7];
    const float* Whh1 = (const float*)d_in[8];
    const float* bih1 = (const float*)d_in[9];
    const float* bhh1 = (const float*)d_in[10];
    const float* Wtgt = (const float*)d_in[11];
    const float* btgt = (const float*)d_in[12];
    const float* muw  = (const float*)d_in[13];
    const float* mub  = (const float*)d_in[14];
    const float* sgw  = (const float*)d_in[15];
    const float* sgb  = (const float*)d_in[16];
    float* out = (float*)d_out;
    char* ws = (char*)d_ws;
    (void)in_sizes; (void)n_in; (void)out_size; (void)ws_size;

    size_t off = 0;
    auto alloc = [&](size_t bytes) {
        size_t o = off;
        off = (off + bytes + 255) & ~(size_t)255;
        return o;
    };
    size_t o_flags = alloc(256);
    size_t o_actr  = alloc((16 * 32 + 64) * 4);  // f0[0..255], f1[256..511], rel0@512, rel1@544
    size_t o_muacc = alloc((size_t)2 * 128 * 8 * 4);
    size_t o_sgacc = alloc((size_t)2 * 128 * 8 * 4);
    size_t zero_end = off;
    size_t o_h0    = alloc((size_t)2 * HT_ELEMS * 2);
    size_t o_h1    = alloc((size_t)2 * HT_ELEMS * 2);
    size_t o_fb2   = alloc((size_t)T_ * 32 * 4 * 512 * 2);

    int*      flags = (int*)(ws + o_flags);
    unsigned* actr  = (unsigned*)(ws + o_actr);
    float*    muacc = (float*)(ws + o_muacc);
    float*    sgacc = (float*)(ws + o_sgacc);
    u16*      h0    = (u16*)(ws + o_h0);
    u16*      h1    = (u16*)(ws + o_h1);
    u16*      fb2   = (u16*)(ws + o_fb2);

    hipMemsetAsync(ws, 0, zero_end, stream);
    detect_mask<<<20, 256, 0, stream>>>((const unsigned*)mask, flags);
    featconv<<<10240, 256, 0, stream>>>(feat, fb2);

    persist<<<NBLK, NT, 0, stream>>>(
        fb2, emb, mask, flags,
        Wih0, Whh0, bih0, bhh0,
        Wih1, Whh1, bih1, bhh1,
        Wtgt, btgt, muw, mub, sgw, sgb,
        h0, h1, muacc, sgacc, actr, out);
}

// Round 12
// 3374.086 us; speedup vs baseline: 1.4777x; 1.0358x over previous
//
#include <hip/hip_runtime.h>

// DeepAR MI355X round 11 (2nd resubmit — infra "container failed twice";
// protocol re-audited for hangs: t=0 boundary, counter monotonicity,
// zeroing lifetime, final waits all traced safe — see session notes):
// arrive-and-release (last arriver publishes).
// r10 post-mortem (-3% vs predicted -25%): the aggregator WGs (blk0/blk128)
// published the release words only after finishing their OWN preceding work
// -> every consumer inherited that latency -> decoupled work re-serialized.
// This round: no aggregators. Single monotone arrival counter per group;
// each arriving WG does FAA (after the proven s_waitcnt(0)+syncthreads data
// drain); the WG seeing n%128==0 is the LAST arriver -- its FAA return
// proves all 127 prior arrivals (and their drained data) are at LLC -- and
// it immediately stores rel = n/128. Publication latency ~= one store.
// Waiters poll one release word (r10-proven traffic). Monotone counters,
// no resets, DAG of waits.
// Schedule per step t:
//   L0: [wait rel1>=t; mu] -> cell0 -> arrive/release f0 ->
//       [wait rel0>=t+1; Whh0 + featlab(t+1) + reduce]   (off-critical)
//   L1: [wait rel1>=t; h1prev-gemm] -> wait rel0>=t+1 -> h0cur-gemm ->
//       reduce -> cell1 -> arrive/release f1
// B=128, T=160, F=512, E=64, H=1024, L=2. Output [B,T,2] fp32.

#define B_   128
#define T_   160
#define FD   512
#define E_   64
#define H_   1024
#define NT   512
#define NBLK 256
#define CH0  100                     // L0 K-chunks (K=1600: 32 feat, 4 lab, 64 h0)
#define CH1  128                     // L1 K-chunks (K=2048: 64 h0cur, 64 h1prev)
#define HT_ELEMS (64 * 4 * 512)      // per-parity h tile elems (= B_*H_)

typedef unsigned short u16;
typedef unsigned long long u64;
typedef __attribute__((ext_vector_type(8))) short bf16x8;
typedef __attribute__((ext_vector_type(16))) float f32x16;

__device__ __forceinline__ bf16x8 ld8(const u16* p) {
    return *reinterpret_cast<const bf16x8*>(p);
}
// coherent (LLC-direct) 16B load as 2x8B relaxed agent atomics — bypasses
// stale L1/L2 without needing a cache-invalidating acquire.
__device__ __forceinline__ bf16x8 ld8c(const u16* p) {
    u64* q = (u64*)p;
    union { u64 v[2]; bf16x8 f; } u_;
    u_.v[0] = __hip_atomic_load(q + 0, __ATOMIC_RELAXED, __HIP_MEMORY_SCOPE_AGENT);
    u_.v[1] = __hip_atomic_load(q + 1, __ATOMIC_RELAXED, __HIP_MEMORY_SCOPE_AGENT);
    return u_.f;
}
__device__ __forceinline__ float4 ld4f(const float* p) {
    u64* q = (u64*)p;
    union { u64 v[2]; float4 f; } u_;
    u_.v[0] = __hip_atomic_load(q + 0, __ATOMIC_RELAXED, __HIP_MEMORY_SCOPE_AGENT);
    u_.v[1] = __hip_atomic_load(q + 1, __ATOMIC_RELAXED, __HIP_MEMORY_SCOPE_AGENT);
    return u_.f;
}
__device__ __forceinline__ f32x16 mfma32(bf16x8 a, bf16x8 b, f32x16 c) {
    return __builtin_amdgcn_mfma_f32_32x32x16_bf16(a, b, c, 0, 0, 0);
}
__device__ __forceinline__ u16 f2bf(float x) {
    unsigned u = __float_as_uint(x);
    u += 0x7FFFu + ((u >> 16) & 1u);   // RNE
    return (u16)(u >> 16);
}
__device__ __forceinline__ float sigm(float x)  { return 1.f / (1.f + __expf(-x)); }
__device__ __forceinline__ float tanh_(float x) { return 1.f - 2.f / (__expf(2.f * x) + 1.f); }
__device__ __forceinline__ float softp(float x) { return x > 20.f ? x : log1pf(__expf(x)); }

__device__ __forceinline__ void st_u32(unsigned* p, unsigned v) {
    __hip_atomic_store(p, v, __ATOMIC_RELAXED, __HIP_MEMORY_SCOPE_AGENT);
}
__device__ __forceinline__ void st_f32(float* p, float v) {
    __hip_atomic_store(p, v, __ATOMIC_RELAXED, __HIP_MEMORY_SCOPE_AGENT);
}

// ---- split-barrier primitives (arrive-and-release topology) ----

// waiter: poll a single release word until >= tgt (r10-proven load level)
__device__ __forceinline__ void wait_rel(unsigned* rel, unsigned tgt) {
    if (threadIdx.x == 0)
        while (__hip_atomic_load(rel, __ATOMIC_RELAXED, __HIP_MEMORY_SCOPE_AGENT) < tgt)
            __builtin_amdgcn_s_sleep(2);
    __atomic_signal_fence(__ATOMIC_ACQUIRE);   // compiler ordering only
    __syncthreads();
}
// arrive: drain this WG's stores/atomics to LLC, FAA the group counter;
// the 128th arriver of each step publishes the release word immediately.
__device__ __forceinline__ void arrive_release(unsigned* cnt, unsigned* rel) {
    __builtin_amdgcn_s_waitcnt(0);   // this wave's stores/atomics at LLC
    __syncthreads();                 // all waves drained
    if (threadIdx.x == 0) {
        unsigned n = __hip_atomic_fetch_add(cnt, 1u, __ATOMIC_RELAXED,
                                            __HIP_MEMORY_SCOPE_AGENT) + 1u;
        if ((n & 127u) == 0u)        // last arriver: all data provably at LLC
            __hip_atomic_store(rel, n >> 7, __ATOMIC_RELAXED,
                               __HIP_MEMORY_SCOPE_AGENT);
    }
}

// ---------------- prologue kernels ----------------

__global__ void detect_mask(const unsigned* __restrict__ m, int* __restrict__ flags) {
    int i = blockIdx.x * 256 + threadIdx.x;   // exactly 5120 words (20480 bytes)
    unsigned w = m[i];
    if (w > 1u) atomicOr(&flags[0], 1);
    if (w != 0u && w != 0x3F800000u) atomicOr(&flags[1], 1);
}

// feat [B][T][512] fp32 -> fb2 [T][c=32][mblk=4][512] bf16 (MFMA A-frag tiles)
__global__ void featconv(const float* __restrict__ feat, u16* __restrict__ fb2) {
    int i = blockIdx.x * 256 + threadIdx.x;   // [0, 160*16384) float4 units
    int t = i >> 14;
    int u = i & 16383;
    int c = u >> 9;
    int r = u & 511;
    int mm = r >> 7;
    int l  = (r >> 1) & 63;
    int jj = r & 1;
    int b = mm * 32 + (l & 31);
    int k = c * 16 + (l >> 5) * 8 + jj * 4;
    float4 v = reinterpret_cast<const float4*>(feat)[((size_t)b * T_ + t) * 128 + (k >> 2)];
    ushort4 o = make_ushort4(f2bf(v.x), f2bf(v.y), f2bf(v.z), f2bf(v.w));
    reinterpret_cast<ushort4*>(fb2)[((((size_t)t * 32 + c) * 4 + mm) * 512 + l * 8 + jj * 4) >> 2] = o;
}

// ---------------- persistent kernel ----------------

struct SM0 {                       // layer-0 WGs
    u16   bw[CH0 * 512];           // 102400 B, B-frags: bw[ch*512 + lane*8 + j]
    float gtb[4224];               // 16896 B: K-reduce scratch [16][256] / gates [128][33]
    float mu_s[128];
    float uu[32], vv[32], bias[32];
    float mwv[8], swv[8];
    unsigned char msk[128];
};
struct SM1 {                       // layer-1 WGs
    u16   bw[CH1 * 512];           // 131072 B
    float gtb[4224];
    float bias[32];
    float mwv[8], swv[8];
};
union SMU { SM0 a; SM1 b; };

__global__ void __launch_bounds__(NT, 2) persist(
    const u16* __restrict__ fb2, const float* __restrict__ emb,
    const void* __restrict__ mask, const int* __restrict__ flags,
    const float* __restrict__ Wih0, const float* __restrict__ Whh0,
    const float* __restrict__ bih0, const float* __restrict__ bhh0,
    const float* __restrict__ Wih1, const float* __restrict__ Whh1,
    const float* __restrict__ bih1, const float* __restrict__ bhh1,
    const float* __restrict__ Wtgt, const float* __restrict__ btgt,
    const float* __restrict__ muw, const float* __restrict__ mubp,
    const float* __restrict__ sgw, const float* __restrict__ sgbp,
    u16* __restrict__ h0T, u16* __restrict__ h1T,
    float* __restrict__ muacc, float* __restrict__ sgacc,
    unsigned* __restrict__ actr,
    float* __restrict__ out)
{
    __shared__ SMU smu;
    const int tid  = threadIdx.x;
    const int blk  = blockIdx.x;
    const bool isL0 = blk < 128;
    const int g    = isL0 ? blk : blk - 128;   // hidden units g*8..g*8+7
    const int wv   = tid >> 6;
    const int m    = wv & 3;                   // M-tile (rows m*32..m*32+31)
    const int s    = wv >> 2;                  // K-split half
    const int lane = tid & 63;
    const int l31  = lane & 31;

    unsigned* f0c  = actr;             // L0 arrival counter (monotone)
    unsigned* f1c  = actr + 32;        // L1 arrival counter
    unsigned* rel0 = actr + 64;        // published by last L0 arriver
    unsigned* rel1 = actr + 96;        // published by last L1 arriver

    const float mub_r = mubp[0], sgb_r = sgbp[0];

    // ---- one-time init: pack weights into MFMA B-frag layout in LDS ----
    if (isL0) {
        SM0& s0 = smu.a;
        for (int i = tid; i < CH0 * 512; i += NT) {
            int ch = i >> 9, r = i & 511, l = r >> 3, jj = r & 7;
            int pc = l & 31;
            int kk = ch * 16 + (l >> 5) * 8 + jj;
            int q = pc & 3, j = pc >> 2;
            int row = q * H_ + g * 8 + j;
            float v = (kk < 576) ? Wih0[row * 576 + kk]
                                 : Whh0[(size_t)row * H_ + (kk - 576)];
            s0.bw[i] = f2bf(v);
        }
        if (tid < 32) {
            int pc = tid, q = pc & 3, j = pc >> 2;
            int row = q * H_ + g * 8 + j;
            s0.bias[pc] = bih0[row] + bhh0[row];
            float su = 0.f, sv = 0.f;
            for (int e = 0; e < 64; ++e) {       // rank-1 label vectors
                float wl = Wih0[row * 576 + 512 + e];
                su += Wtgt[e] * wl;
                sv += btgt[e] * wl;
            }
            s0.uu[pc] = su; s0.vv[pc] = sv;
        }
        if (tid < 8) {
            int h = g * 8 + tid;
            s0.mwv[tid] = muw[2 * h]; s0.swv[tid] = sgw[2 * h];
        }
    } else {
        SM1& s1 = smu.b;
        for (int i = tid; i < CH1 * 512; i += NT) {
            int ch = i >> 9, r = i & 511, l = r >> 3, jj = r & 7;
            int pc = l & 31;
            int kk = ch * 16 + (l >> 5) * 8 + jj;
            int q = pc & 3, j = pc >> 2;
            int row = q * H_ + g * 8 + j;
            float v = (kk < 1024) ? Wih1[(size_t)row * H_ + kk]
                                  : Whh1[(size_t)row * H_ + (kk - 1024)];
            s1.bw[i] = f2bf(v);
        }
        if (tid < 32) {
            int pc = tid, q = pc & 3, j = pc >> 2;
            int row = q * H_ + g * 8 + j;
            s1.bias[pc] = bih1[row] + bhh1[row];
        }
        if (tid < 8) {
            int h = g * 8 + tid;
            s1.mwv[tid] = muw[2 * h + 1]; s1.swv[tid] = sgw[2 * h + 1];
        }
    }
    const int nonbin = flags[0], nonfl = flags[1];
    __syncthreads();

    float creg0 = 0.f, creg1 = 0.f;
    f32x16 acc;
    #pragma unroll
    for (int r = 0; r < 16; ++r) acc[r] = 0.f;

    // K-split reduce: acc (both halves) -> gates in gtb[128][33]; zeroes acc.
    auto reduce_gates = [&](float* g_) {
        if (s == 1) {
            #pragma unroll
            for (int r = 0; r < 16; ++r) g_[r * 256 + m * 64 + lane] = acc[r];
        }
        __syncthreads();
        f32x16 tot;
        if (s == 0) {
            #pragma unroll
            for (int r = 0; r < 16; ++r) tot[r] = acc[r] + g_[r * 256 + m * 64 + lane];
        }
        __syncthreads();
        if (s == 0) {
            #pragma unroll
            for (int r = 0; r < 16; ++r) {
                int row = m * 32 + (r & 3) + 8 * (r >> 2) + 4 * (lane >> 5);
                g_[row * 33 + l31] = tot[r];
            }
        }
        #pragma unroll
        for (int r = 0; r < 16; ++r) acc[r] = 0.f;
    };

    // 32-chunk h-GEMM with full-depth register prefetch (r8).
    auto hgemm = [&](const u16* hp, const u16* bwb) {
        bf16x8 areg[32];
        #pragma unroll
        for (int c = 0; c < 32; ++c) {
            int ch = s * 32 + c;
            areg[c] = ld8c(hp + ((size_t)ch * 4 + m) * 512 + lane * 8);
        }
        #pragma unroll
        for (int c = 0; c < 32; ++c) {
            int ch = s * 32 + c;
            bf16x8 b = *(const bf16x8*)&bwb[ch * 512 + lane * 8];
            acc = mfma32(areg[c], b, acc);
        }
    };

    // feat+label GEMM for step t1 (chunks 0..35, s-split 18 each).
    // Labels (chunks 32..35, s==1 only) built in REGISTERS (r7).
    auto featlab = [&](int t1, bool use_mask) {
        SM0& s0 = smu.a;
        const int bq = m * 32 + l31;
        bool um = false;
        if (use_mask && s == 1) {
            int mi = bq * T_ + t1;
            um = !nonbin ? (reinterpret_cast<const int*>(mask)[mi] != 0)
               : !nonfl  ? (reinterpret_cast<const float*>(mask)[mi] != 0.f)
                         : (reinterpret_cast<const unsigned char*>(mask)[mi] != 0);
        }
        #pragma unroll 6
        for (int c = 0; c < 18; ++c) {
            int ch = s * 18 + c;
            bf16x8 a;
            if (ch < 32) {
                a = ld8(fb2 + (((size_t)t1 * 32 + ch) * 4 + m) * 512 + lane * 8);
            } else {
                const float* ep = &emb[((size_t)bq * T_ + t1) * 64
                                       + (ch - 32) * 16 + (lane >> 5) * 8];
                float4 v0 = *reinterpret_cast<const float4*>(ep);
                float4 v1 = *reinterpret_cast<const float4*>(ep + 4);
                if (um) { v0.x=v0.y=v0.z=v0.w=0.f; v1.x=v1.y=v1.z=v1.w=0.f; }
                a[0] = (short)f2bf(v0.x); a[1] = (short)f2bf(v0.y);
                a[2] = (short)f2bf(v0.z); a[3] = (short)f2bf(v0.w);
                a[4] = (short)f2bf(v1.x); a[5] = (short)f2bf(v1.y);
                a[6] = (short)f2bf(v1.z); a[7] = (short)f2bf(v1.w);
            }
            bf16x8 b = *(const bf16x8*)&s0.bw[ch * 512 + lane * 8];
            acc = mfma32(a, b, acc);
        }
    };

    // pre-loop: gates0(0) = feat(0)+lab(0) GEMM, reduced into gtb
    if (isL0) {
        featlab(0, false);
        reduce_gates(smu.a.gtb);
    }

    for (int t = 0; t < T_; ++t) {
        const int pcur = t & 1, pprev = pcur ^ 1;

        if (isL0) {
            SM0& s0 = smu.a;
            // -------- critical: mu(t-1) -> cell0(t) -> publish h0(t) --------
            if (t > 0) {
                wait_rel(rel1, (unsigned)t);       // h1(t-1)+partials at LLC
                if (tid < 128) {
                    float4 x = ld4f(&muacc[(pprev * 128 + tid) * 8]);
                    float4 y = ld4f(&muacc[(pprev * 128 + tid) * 8 + 4]);
                    s0.mu_s[tid] = (x.x + x.y) + (x.z + x.w) + (y.x + y.y) + (y.z + y.w) + mub_r;
                    int mi = tid * T_ + t;
                    bool um = !nonbin ? (reinterpret_cast<const int*>(mask)[mi] != 0)
                            : !nonfl  ? (reinterpret_cast<const float*>(mask)[mi] != 0.f)
                                      : (reinterpret_cast<const unsigned char*>(mask)[mi] != 0);
                    s0.msk[tid] = um ? 1 : 0;
                }
            }
            __syncthreads();
            if (t > 0 && tid == 0) {
                float4 x = ld4f(&sgacc[(pprev * 128 + g) * 8]);
                float4 y = ld4f(&sgacc[(pprev * 128 + g) * 8 + 4]);
                float sg = (x.x + x.y) + (x.z + x.w) + (y.x + y.y) + (y.z + y.w) + sgb_r;
                out[((size_t)g * T_ + (t - 1)) * 2 + 0] = s0.mu_s[g];
                out[((size_t)g * T_ + (t - 1)) * 2 + 1] = softp(sg);
            }
            // cell0 + h0 publish (fragment-tiled, full-line) + partial atomics
            u16* hw = h0T + (size_t)pcur * HT_ELEMS;
            const int c_ = g >> 1, half = g & 1;
            #pragma unroll
            for (int p = 0; p < 2; ++p) {
                int id = tid + p * NT;
                int b = id >> 3, j = id & 7;
                float gi = s0.gtb[b * 33 + 4 * j + 0] + s0.bias[4 * j + 0];
                float gf = s0.gtb[b * 33 + 4 * j + 1] + s0.bias[4 * j + 1];
                float gg = s0.gtb[b * 33 + 4 * j + 2] + s0.bias[4 * j + 2];
                float go = s0.gtb[b * 33 + 4 * j + 3] + s0.bias[4 * j + 3];
                if (t > 0 && s0.msk[b]) {       // rank-1 mu-label term (fp32 exact)
                    float mu = s0.mu_s[b];
                    gi += mu * s0.uu[4 * j + 0] + s0.vv[4 * j + 0];
                    gf += mu * s0.uu[4 * j + 1] + s0.vv[4 * j + 1];
                    gg += mu * s0.uu[4 * j + 2] + s0.vv[4 * j + 2];
                    go += mu * s0.uu[4 * j + 3] + s0.vv[4 * j + 3];
                }
                float cold = (p == 0) ? creg0 : creg1;
                float cn = sigm(gf) * cold + sigm(gi) * tanh_(gg);
                float hn = sigm(go) * tanh_(cn);
                if (p == 0) creg0 = cn; else creg1 = cn;
                unsigned hv = f2bf(hn);
                unsigned other = (unsigned)__shfl_xor((int)hv, 1);
                if ((j & 1) == 0) {
                    int l = half * 32 + (b & 31), mb = b >> 5;
                    st_u32(reinterpret_cast<unsigned*>(hw + ((size_t)(c_ * 4 + mb) * 512 + l * 8 + j)),
                           hv | (other << 16));
                }
                float pmu = hn * s0.mwv[j], psg = hn * s0.swv[j];
                pmu += __shfl_xor(pmu, 1); pmu += __shfl_xor(pmu, 2); pmu += __shfl_xor(pmu, 4);
                psg += __shfl_xor(psg, 1); psg += __shfl_xor(psg, 2); psg += __shfl_xor(psg, 4);
                if (j == 0) {
                    atomicAdd(&muacc[(pcur * 128 + b) * 8 + (g & 7)], pmu);
                    atomicAdd(&sgacc[(pcur * 128 + b) * 8 + (g & 7)], psg);
                }
            }
            arrive_release(f0c, rel0);            // last arriver -> rel0=t+1

            // -------- off-critical: gates0(t+1), overlaps L1's chain --------
            if (t + 1 < T_) {
                wait_rel(rel0, (unsigned)(t + 1));      // all h0(t) slices
                hgemm(h0T + (size_t)pcur * HT_ELEMS, &s0.bw[36 * 512]);
                featlab(t + 1, true);
                reduce_gates(s0.gtb);
            }
        } else {
            SM1& s1 = smu.b;
            // -------- h1prev GEMM first: overlaps L0's cell0 --------
            if (t > 0) {
                wait_rel(rel1, (unsigned)t);      // own group, nearly free
                hgemm(h1T + (size_t)pprev * HT_ELEMS, &s1.bw[64 * 512]);
            }
            // -------- critical: h0(t) -> gates1 -> cell1 -> publish ---------
            wait_rel(rel0, (unsigned)(t + 1));          // h0(t) at LLC
            if (t > 0 && tid < 8) {     // zero consumed parity slots:
                // safe: rel0>=t+1 => all L0 read mu(t-1); step-t+1 writers
                // are gated behind rel1=t+1 which is after this WG's arrive.
                st_f32(&muacc[(pprev * 128 + g) * 8 + tid], 0.f);
                st_f32(&sgacc[(pprev * 128 + g) * 8 + tid], 0.f);
            }
            hgemm(h0T + (size_t)pcur * HT_ELEMS, &s1.bw[0]);        // h0cur
            reduce_gates(s1.gtb);
            __syncthreads();
            // cell1 + h1 publish + partial atomics
            u16* hw = h1T + (size_t)pcur * HT_ELEMS;
            const int c_ = g >> 1, half = g & 1;
            #pragma unroll
            for (int p = 0; p < 2; ++p) {
                int id = tid + p * NT;
                int b = id >> 3, j = id & 7;
                float gi = s1.gtb[b * 33 + 4 * j + 0] + s1.bias[4 * j + 0];
                float gf = s1.gtb[b * 33 + 4 * j + 1] + s1.bias[4 * j + 1];
                float gg = s1.gtb[b * 33 + 4 * j + 2] + s1.bias[4 * j + 2];
                float go = s1.gtb[b * 33 + 4 * j + 3] + s1.bias[4 * j + 3];
                float cold = (p == 0) ? creg0 : creg1;
                float cn = sigm(gf) * cold + sigm(gi) * tanh_(gg);
                float hn = sigm(go) * tanh_(cn);
                if (p == 0) creg0 = cn; else creg1 = cn;
                unsigned hv = f2bf(hn);
                unsigned other = (unsigned)__shfl_xor((int)hv, 1);
                if ((j & 1) == 0) {
                    int l = half * 32 + (b & 31), mb = b >> 5;
                    st_u32(reinterpret_cast<unsigned*>(hw + ((size_t)(c_ * 4 + mb) * 512 + l * 8 + j)),
                           hv | (other << 16));
                }
                float pmu = hn * s1.mwv[j], psg = hn * s1.swv[j];
                pmu += __shfl_xor(pmu, 1); pmu += __shfl_xor(pmu, 2); pmu += __shfl_xor(pmu, 4);
                psg += __shfl_xor(psg, 1); psg += __shfl_xor(psg, 2); psg += __shfl_xor(psg, 4);
                if (j == 0) {
                    atomicAdd(&muacc[(pcur * 128 + b) * 8 + (g & 7)], pmu);
                    atomicAdd(&sgacc[(pcur * 128 + b) * 8 + (g & 7)], psg);
                }
            }
            arrive_release(f1c, rel1);            // last arriver -> rel1=t+1
        }
    }

    // ---- final output t = T_-1 (parity 1) ----
    if (isL0) {
        wait_rel(rel1, (unsigned)T_);             // h1(T-1) partials at LLC
        if (tid == 0) {
            float4 x = ld4f(&muacc[(1 * 128 + g) * 8]);
            float4 y = ld4f(&muacc[(1 * 128 + g) * 8 + 4]);
            float mu = (x.x + x.y) + (x.z + x.w) + (y.x + y.y) + (y.z + y.w) + mub_r;
            float4 z = ld4f(&sgacc[(1 * 128 + g) * 8]);
            float4 u2 = ld4f(&sgacc[(1 * 128 + g) * 8 + 4]);
            float sg = (z.x + z.y) + (z.z + z.w) + (u2.x + u2.y) + (u2.z + u2.w) + sgb_r;
            out[((size_t)g * T_ + (T_ - 1)) * 2 + 0] = mu;
            out[((size_t)g * T_ + (T_ - 1)) * 2 + 1] = softp(sg);
        }
    }
}

// ---------------- host ----------------

extern "C" void kernel_launch(void* const* d_in, const int* in_sizes, int n_in,
                              void* d_out, int out_size, void* d_ws, size_t ws_size,
                              hipStream_t stream) {
    const float* feat = (const float*)d_in[0];
    const float* emb  = (const float*)d_in[1];
    const void*  mask = d_in[2];
    const float* Wih0 = (const float*)d_in[3];
    const float* Whh0 = (const float*)d_in[4];
    const float* bih0 = (const float*)d_in[5];
    const float* bhh0 = (const float*)d_in[6];
    const float* Wih1 = (const float*)d_in[7];
    const float* Whh1 = (const float*)d_in[8];
    const float* bih1 = (const float*)d_in[9];
    const float* bhh1 = (const float*)d_in[10];
    const float* Wtgt = (const float*)d_in[11];
    const float* btgt = (const float*)d_in[12];
    const float* muw  = (const float*)d_in[13];
    const float* mub  = (const float*)d_in[14];
    const float* sgw  = (const float*)d_in[15];
    const float* sgb  = (const float*)d_in[16];
    float* out = (float*)d_out;
    char* ws = (char*)d_ws;
    (void)in_sizes; (void)n_in; (void)out_size; (void)ws_size;

    size_t off = 0;
    auto alloc = [&](size_t bytes) {
        size_t o = off;
        off = (off + bytes + 255) & ~(size_t)255;
        return o;
    };
    size_t o_flags = alloc(256);
    size_t o_actr  = alloc(4 * 32 * 4);   // f0c@0, f1c@32, rel0@64, rel1@96 (u32 idx)
    size_t o_muacc = alloc((size_t)2 * 128 * 8 * 4);
    size_t o_sgacc = alloc((size_t)2 * 128 * 8 * 4);
    size_t zero_end = off;
    size_t o_h0    = alloc((size_t)2 * HT_ELEMS * 2);
    size_t o_h1    = alloc((size_t)2 * HT_ELEMS * 2);
    size_t o_fb2   = alloc((size_t)T_ * 32 * 4 * 512 * 2);

    int*      flags = (int*)(ws + o_flags);
    unsigned* actr  = (unsigned*)(ws + o_actr);
    float*    muacc = (float*)(ws + o_muacc);
    float*    sgacc = (float*)(ws + o_sgacc);
    u16*      h0    = (u16*)(ws + o_h0);
    u16*      h1    = (u16*)(ws + o_h1);
    u16*      fb2   = (u16*)(ws + o_fb2);

    hipMemsetAsync(ws, 0, zero_end, stream);
    detect_mask<<<20, 256, 0, stream>>>((const unsigned*)mask, flags);
    featconv<<<10240, 256, 0, stream>>>(feat, fb2);

    persist<<<NBLK, NT, 0, stream>>>(
        fb2, emb, mask, flags,
        Wih0, Whh0, bih0, bhh0,
        Wih1, Whh1, bih1, bhh1,
        Wtgt, btgt, muw, mub, sgw, sgb,
        h0, h1, muacc, sgacc, actr, out);
}

// Round 14
// 3282.183 us; speedup vs baseline: 1.5191x; 1.0280x over previous
//
#include <hip/hip_runtime.h>

// DeepAR MI355X round 12 (resubmit — broker timeout, never benched):
// cached h-tile reads + per-wait L2 acquire-inv.
// r9-r11 post-mortem: all sync restructures ~null; the binder is LLC READ
// THROUGHPUT on h-tiles. 96 MB/step (each of 128 WGs reads each full 256KB
// tile) via 8B agent-ATOMIC loads = 12.6M LLC atomic ops/step ~= 4.6 TB/s
// effective — the ceiling. Evidence: r9's poll storm (+1e9 LLC ops/s)
// slowed ALL phases 38% (LLC ops are the scarce resource); r8 prefetch flat
// (bandwidth- not latency-bound); r10/r11 overlap flat (same saturated LLC).
// Fix: h-tile reads revert to PLAIN cached loads (coalesced dwordx4,
// L2-cached; 16 WGs/XCD share the L2 copy -> LLC traffic /16) + the
// r5-PROVEN one-acquire-inv-per-WG placed at each consuming wait
// (wait_rel(acq=true): poll relaxed, then one __ATOMIC_ACQUIRE load ->
// buffer_inv of L1+L2, then __syncthreads). Writers unchanged (drain to
// LLC before FAA). mu/sg partial reads stay atomic (tiny).
// Staleness audit: every mutable-data read sits behind wait->inv->sync;
// parity-slot reuse distance 2 steps, inv at each consuming wait covers.
// Sync scheme unchanged from r11 (arrive-and-release, monotone counters).
// B=128, T=160, F=512, E=64, H=1024, L=2. Output [B,T,2] fp32.

#define B_   128
#define T_   160
#define FD   512
#define E_   64
#define H_   1024
#define NT   512
#define NBLK 256
#define CH0  100                     // L0 K-chunks (K=1600: 32 feat, 4 lab, 64 h0)
#define CH1  128                     // L1 K-chunks (K=2048: 64 h0cur, 64 h1prev)
#define HT_ELEMS (64 * 4 * 512)      // per-parity h tile elems (= B_*H_)

typedef unsigned short u16;
typedef unsigned long long u64;
typedef __attribute__((ext_vector_type(8))) short bf16x8;
typedef __attribute__((ext_vector_type(16))) float f32x16;

__device__ __forceinline__ bf16x8 ld8(const u16* p) {
    return *reinterpret_cast<const bf16x8*>(p);
}
// small coherent reads (mu/sig partials) — LLC-direct atomics, low volume
__device__ __forceinline__ float4 ld4f(const float* p) {
    u64* q = (u64*)p;
    union { u64 v[2]; float4 f; } u_;
    u_.v[0] = __hip_atomic_load(q + 0, __ATOMIC_RELAXED, __HIP_MEMORY_SCOPE_AGENT);
    u_.v[1] = __hip_atomic_load(q + 1, __ATOMIC_RELAXED, __HIP_MEMORY_SCOPE_AGENT);
    return u_.f;
}
__device__ __forceinline__ f32x16 mfma32(bf16x8 a, bf16x8 b, f32x16 c) {
    return __builtin_amdgcn_mfma_f32_32x32x16_bf16(a, b, c, 0, 0, 0);
}
__device__ __forceinline__ u16 f2bf(float x) {
    unsigned u = __float_as_uint(x);
    u += 0x7FFFu + ((u >> 16) & 1u);   // RNE
    return (u16)(u >> 16);
}
__device__ __forceinline__ float sigm(float x)  { return 1.f / (1.f + __expf(-x)); }
__device__ __forceinline__ float tanh_(float x) { return 1.f - 2.f / (__expf(2.f * x) + 1.f); }
__device__ __forceinline__ float softp(float x) { return x > 20.f ? x : log1pf(__expf(x)); }

__device__ __forceinline__ void st_u32(unsigned* p, unsigned v) {
    __hip_atomic_store(p, v, __ATOMIC_RELAXED, __HIP_MEMORY_SCOPE_AGENT);
}
__device__ __forceinline__ void st_f32(float* p, float v) {
    __hip_atomic_store(p, v, __ATOMIC_RELAXED, __HIP_MEMORY_SCOPE_AGENT);
}

// ---- split-barrier primitives (arrive-and-release + optional acquire) ----

// waiter: poll one release word; if acq, ONE acquire load (L1+L2 inv,
// r5-proven "one inv per WG per barrier" pattern) before releasing the WG.
__device__ __forceinline__ void wait_rel(unsigned* rel, unsigned tgt, bool acq) {
    if (threadIdx.x == 0) {
        while (__hip_atomic_load(rel, __ATOMIC_RELAXED, __HIP_MEMORY_SCOPE_AGENT) < tgt)
            __builtin_amdgcn_s_sleep(2);
        if (acq)
            (void)__hip_atomic_load(rel, __ATOMIC_ACQUIRE, __HIP_MEMORY_SCOPE_AGENT);
    }
    __atomic_signal_fence(__ATOMIC_ACQUIRE);   // compiler ordering
    __syncthreads();
}
// arrive: drain this WG's stores/atomics to LLC, FAA the group counter;
// the 128th arriver of each step publishes the release word immediately.
__device__ __forceinline__ void arrive_release(unsigned* cnt, unsigned* rel) {
    __builtin_amdgcn_s_waitcnt(0);   // this wave's stores/atomics at LLC
    __syncthreads();                 // all waves drained
    if (threadIdx.x == 0) {
        unsigned n = __hip_atomic_fetch_add(cnt, 1u, __ATOMIC_RELAXED,
                                            __HIP_MEMORY_SCOPE_AGENT) + 1u;
        if ((n & 127u) == 0u)        // last arriver: all data provably at LLC
            __hip_atomic_store(rel, n >> 7, __ATOMIC_RELAXED,
                               __HIP_MEMORY_SCOPE_AGENT);
    }
}

// ---------------- prologue kernels ----------------

__global__ void detect_mask(const unsigned* __restrict__ m, int* __restrict__ flags) {
    int i = blockIdx.x * 256 + threadIdx.x;   // exactly 5120 words (20480 bytes)
    unsigned w = m[i];
    if (w > 1u) atomicOr(&flags[0], 1);
    if (w != 0u && w != 0x3F800000u) atomicOr(&flags[1], 1);
}

// feat [B][T][512] fp32 -> fb2 [T][c=32][mblk=4][512] bf16 (MFMA A-frag tiles)
__global__ void featconv(const float* __restrict__ feat, u16* __restrict__ fb2) {
    int i = blockIdx.x * 256 + threadIdx.x;   // [0, 160*16384) float4 units
    int t = i >> 14;
    int u = i & 16383;
    int c = u >> 9;
    int r = u & 511;
    int mm = r >> 7;
    int l  = (r >> 1) & 63;
    int jj = r & 1;
    int b = mm * 32 + (l & 31);
    int k = c * 16 + (l >> 5) * 8 + jj * 4;
    float4 v = reinterpret_cast<const float4*>(feat)[((size_t)b * T_ + t) * 128 + (k >> 2)];
    ushort4 o = make_ushort4(f2bf(v.x), f2bf(v.y), f2bf(v.z), f2bf(v.w));
    reinterpret_cast<ushort4*>(fb2)[((((size_t)t * 32 + c) * 4 + mm) * 512 + l * 8 + jj * 4) >> 2] = o;
}

// ---------------- persistent kernel ----------------

struct SM0 {                       // layer-0 WGs
    u16   bw[CH0 * 512];           // 102400 B, B-frags: bw[ch*512 + lane*8 + j]
    float gtb[4224];               // 16896 B: K-reduce scratch [16][256] / gates [128][33]
    float mu_s[128];
    float uu[32], vv[32], bias[32];
    float mwv[8], swv[8];
    unsigned char msk[128];
};
struct SM1 {                       // layer-1 WGs
    u16   bw[CH1 * 512];           // 131072 B
    float gtb[4224];
    float bias[32];
    float mwv[8], swv[8];
};
union SMU { SM0 a; SM1 b; };

__global__ void __launch_bounds__(NT, 2) persist(
    const u16* __restrict__ fb2, const float* __restrict__ emb,
    const void* __restrict__ mask, const int* __restrict__ flags,
    const float* __restrict__ Wih0, const float* __restrict__ Whh0,
    const float* __restrict__ bih0, const float* __restrict__ bhh0,
    const float* __restrict__ Wih1, const float* __restrict__ Whh1,
    const float* __restrict__ bih1, const float* __restrict__ bhh1,
    const float* __restrict__ Wtgt, const float* __restrict__ btgt,
    const float* __restrict__ muw, const float* __restrict__ mubp,
    const float* __restrict__ sgw, const float* __restrict__ sgbp,
    u16* __restrict__ h0T, u16* __restrict__ h1T,
    float* __restrict__ muacc, float* __restrict__ sgacc,
    unsigned* __restrict__ actr,
    float* __restrict__ out)
{
    __shared__ SMU smu;
    const int tid  = threadIdx.x;
    const int blk  = blockIdx.x;
    const bool isL0 = blk < 128;
    const int g    = isL0 ? blk : blk - 128;   // hidden units g*8..g*8+7
    const int wv   = tid >> 6;
    const int m    = wv & 3;                   // M-tile (rows m*32..m*32+31)
    const int s    = wv >> 2;                  // K-split half
    const int lane = tid & 63;
    const int l31  = lane & 31;

    unsigned* f0c  = actr;             // L0 arrival counter (monotone)
    unsigned* f1c  = actr + 32;        // L1 arrival counter
    unsigned* rel0 = actr + 64;        // published by last L0 arriver
    unsigned* rel1 = actr + 96;        // published by last L1 arriver

    const float mub_r = mubp[0], sgb_r = sgbp[0];

    // ---- one-time init: pack weights into MFMA B-frag layout in LDS ----
    if (isL0) {
        SM0& s0 = smu.a;
        for (int i = tid; i < CH0 * 512; i += NT) {
            int ch = i >> 9, r = i & 511, l = r >> 3, jj = r & 7;
            int pc = l & 31;
            int kk = ch * 16 + (l >> 5) * 8 + jj;
            int q = pc & 3, j = pc >> 2;
            int row = q * H_ + g * 8 + j;
            float v = (kk < 576) ? Wih0[row * 576 + kk]
                                 : Whh0[(size_t)row * H_ + (kk - 576)];
            s0.bw[i] = f2bf(v);
        }
        if (tid < 32) {
            int pc = tid, q = pc & 3, j = pc >> 2;
            int row = q * H_ + g * 8 + j;
            s0.bias[pc] = bih0[row] + bhh0[row];
            float su = 0.f, sv = 0.f;
            for (int e = 0; e < 64; ++e) {       // rank-1 label vectors
                float wl = Wih0[row * 576 + 512 + e];
                su += Wtgt[e] * wl;
                sv += btgt[e] * wl;
            }
            s0.uu[pc] = su; s0.vv[pc] = sv;
        }
        if (tid < 8) {
            int h = g * 8 + tid;
            s0.mwv[tid] = muw[2 * h]; s0.swv[tid] = sgw[2 * h];
        }
    } else {
        SM1& s1 = smu.b;
        for (int i = tid; i < CH1 * 512; i += NT) {
            int ch = i >> 9, r = i & 511, l = r >> 3, jj = r & 7;
            int pc = l & 31;
            int kk = ch * 16 + (l >> 5) * 8 + jj;
            int q = pc & 3, j = pc >> 2;
            int row = q * H_ + g * 8 + j;
            float v = (kk < 1024) ? Wih1[(size_t)row * H_ + kk]
                                  : Whh1[(size_t)row * H_ + (kk - 1024)];
            s1.bw[i] = f2bf(v);
        }
        if (tid < 32) {
            int pc = tid, q = pc & 3, j = pc >> 2;
            int row = q * H_ + g * 8 + j;
            s1.bias[pc] = bih1[row] + bhh1[row];
        }
        if (tid < 8) {
            int h = g * 8 + tid;
            s1.mwv[tid] = muw[2 * h + 1]; s1.swv[tid] = sgw[2 * h + 1];
        }
    }
    const int nonbin = flags[0], nonfl = flags[1];
    __syncthreads();

    float creg0 = 0.f, creg1 = 0.f;
    f32x16 acc;
    #pragma unroll
    for (int r = 0; r < 16; ++r) acc[r] = 0.f;

    // K-split reduce: acc (both halves) -> gates in gtb[128][33]; zeroes acc.
    auto reduce_gates = [&](float* g_) {
        if (s == 1) {
            #pragma unroll
            for (int r = 0; r < 16; ++r) g_[r * 256 + m * 64 + lane] = acc[r];
        }
        __syncthreads();
        f32x16 tot;
        if (s == 0) {
            #pragma unroll
            for (int r = 0; r < 16; ++r) tot[r] = acc[r] + g_[r * 256 + m * 64 + lane];
        }
        __syncthreads();
        if (s == 0) {
            #pragma unroll
            for (int r = 0; r < 16; ++r) {
                int row = m * 32 + (r & 3) + 8 * (r >> 2) + 4 * (lane >> 5);
                g_[row * 33 + l31] = tot[r];
            }
        }
        #pragma unroll
        for (int r = 0; r < 16; ++r) acc[r] = 0.f;
    };

    // 32-chunk h-GEMM, PLAIN cached loads (L2-shared across the XCD's WGs),
    // full-depth register prefetch retained (hides L2-miss latency).
    auto hgemm = [&](const u16* hp, const u16* bwb) {
        bf16x8 areg[32];
        #pragma unroll
        for (int c = 0; c < 32; ++c) {
            int ch = s * 32 + c;
            areg[c] = ld8(hp + ((size_t)ch * 4 + m) * 512 + lane * 8);
        }
        #pragma unroll
        for (int c = 0; c < 32; ++c) {
            int ch = s * 32 + c;
            bf16x8 b = *(const bf16x8*)&bwb[ch * 512 + lane * 8];
            acc = mfma32(areg[c], b, acc);
        }
    };

    // feat+label GEMM for step t1 (chunks 0..35, s-split 18 each).
    // Labels (chunks 32..35, s==1 only) built in REGISTERS (r7).
    auto featlab = [&](int t1, bool use_mask) {
        SM0& s0 = smu.a;
        const int bq = m * 32 + l31;
        bool um = false;
        if (use_mask && s == 1) {
            int mi = bq * T_ + t1;
            um = !nonbin ? (reinterpret_cast<const int*>(mask)[mi] != 0)
               : !nonfl  ? (reinterpret_cast<const float*>(mask)[mi] != 0.f)
                         : (reinterpret_cast<const unsigned char*>(mask)[mi] != 0);
        }
        #pragma unroll 6
        for (int c = 0; c < 18; ++c) {
            int ch = s * 18 + c;
            bf16x8 a;
            if (ch < 32) {
                a = ld8(fb2 + (((size_t)t1 * 32 + ch) * 4 + m) * 512 + lane * 8);
            } else {
                const float* ep = &emb[((size_t)bq * T_ + t1) * 64
                                       + (ch - 32) * 16 + (lane >> 5) * 8];
                float4 v0 = *reinterpret_cast<const float4*>(ep);
                float4 v1 = *reinterpret_cast<const float4*>(ep + 4);
                if (um) { v0.x=v0.y=v0.z=v0.w=0.f; v1.x=v1.y=v1.z=v1.w=0.f; }
                a[0] = (short)f2bf(v0.x); a[1] = (short)f2bf(v0.y);
                a[2] = (short)f2bf(v0.z); a[3] = (short)f2bf(v0.w);
                a[4] = (short)f2bf(v1.x); a[5] = (short)f2bf(v1.y);
                a[6] = (short)f2bf(v1.z); a[7] = (short)f2bf(v1.w);
            }
            bf16x8 b = *(const bf16x8*)&s0.bw[ch * 512 + lane * 8];
            acc = mfma32(a, b, acc);
        }
    };

    // pre-loop: gates0(0) = feat(0)+lab(0) GEMM, reduced into gtb
    if (isL0) {
        featlab(0, false);
        reduce_gates(smu.a.gtb);
    }

    for (int t = 0; t < T_; ++t) {
        const int pcur = t & 1, pprev = pcur ^ 1;

        if (isL0) {
            SM0& s0 = smu.a;
            // -------- critical: mu(t-1) -> cell0(t) -> publish h0(t) --------
            if (t > 0) {
                wait_rel(rel1, (unsigned)t, false);  // mu via atomics, no inv
                if (tid < 128) {
                    float4 x = ld4f(&muacc[(pprev * 128 + tid) * 8]);
                    float4 y = ld4f(&muacc[(pprev * 128 + tid) * 8 + 4]);
                    s0.mu_s[tid] = (x.x + x.y) + (x.z + x.w) + (y.x + y.y) + (y.z + y.w) + mub_r;
                    int mi = tid * T_ + t;
                    bool um = !nonbin ? (reinterpret_cast<const int*>(mask)[mi] != 0)
                            : !nonfl  ? (reinterpret_cast<const float*>(mask)[mi] != 0.f)
                                      : (reinterpret_cast<const unsigned char*>(mask)[mi] != 0);
                    s0.msk[tid] = um ? 1 : 0;
                }
            }
            __syncthreads();
            if (t > 0 && tid == 0) {
                float4 x = ld4f(&sgacc[(pprev * 128 + g) * 8]);
                float4 y = ld4f(&sgacc[(pprev * 128 + g) * 8 + 4]);
                float sg = (x.x + x.y) + (x.z + x.w) + (y.x + y.y) + (y.z + y.w) + sgb_r;
                out[((size_t)g * T_ + (t - 1)) * 2 + 0] = s0.mu_s[g];
                out[((size_t)g * T_ + (t - 1)) * 2 + 1] = softp(sg);
            }
            // cell0 + h0 publish (fragment-tiled, full-line) + partial atomics
            u16* hw = h0T + (size_t)pcur * HT_ELEMS;
            const int c_ = g >> 1, half = g & 1;
            #pragma unroll
            for (int p = 0; p < 2; ++p) {
                int id = tid + p * NT;
                int b = id >> 3, j = id & 7;
                float gi = s0.gtb[b * 33 + 4 * j + 0] + s0.bias[4 * j + 0];
                float gf = s0.gtb[b * 33 + 4 * j + 1] + s0.bias[4 * j + 1];
                float gg = s0.gtb[b * 33 + 4 * j + 2] + s0.bias[4 * j + 2];
                float go = s0.gtb[b * 33 + 4 * j + 3] + s0.bias[4 * j + 3];
                if (t > 0 && s0.msk[b]) {       // rank-1 mu-label term (fp32 exact)
                    float mu = s0.mu_s[b];
                    gi += mu * s0.uu[4 * j + 0] + s0.vv[4 * j + 0];
                    gf += mu * s0.uu[4 * j + 1] + s0.vv[4 * j + 1];
                    gg += mu * s0.uu[4 * j + 2] + s0.vv[4 * j + 2];
                    go += mu * s0.uu[4 * j + 3] + s0.vv[4 * j + 3];
                }
                float cold = (p == 0) ? creg0 : creg1;
                float cn = sigm(gf) * cold + sigm(gi) * tanh_(gg);
                float hn = sigm(go) * tanh_(cn);
                if (p == 0) creg0 = cn; else creg1 = cn;
                unsigned hv = f2bf(hn);
                unsigned other = (unsigned)__shfl_xor((int)hv, 1);
                if ((j & 1) == 0) {
                    int l = half * 32 + (b & 31), mb = b >> 5;
                    st_u32(reinterpret_cast<unsigned*>(hw + ((size_t)(c_ * 4 + mb) * 512 + l * 8 + j)),
                           hv | (other << 16));
                }
                float pmu = hn * s0.mwv[j], psg = hn * s0.swv[j];
                pmu += __shfl_xor(pmu, 1); pmu += __shfl_xor(pmu, 2); pmu += __shfl_xor(pmu, 4);
                psg += __shfl_xor(psg, 1); psg += __shfl_xor(psg, 2); psg += __shfl_xor(psg, 4);
                if (j == 0) {
                    atomicAdd(&muacc[(pcur * 128 + b) * 8 + (g & 7)], pmu);
                    atomicAdd(&sgacc[(pcur * 128 + b) * 8 + (g & 7)], psg);
                }
            }
            arrive_release(f0c, rel0);            // last arriver -> rel0=t+1

            // -------- off-critical: gates0(t+1), overlaps L1's chain --------
            if (t + 1 < T_) {
                wait_rel(rel0, (unsigned)(t + 1), true);  // inv, then cached h0
                hgemm(h0T + (size_t)pcur * HT_ELEMS, &s0.bw[36 * 512]);
                featlab(t + 1, true);
                reduce_gates(s0.gtb);
            }
        } else {
            SM1& s1 = smu.b;
            // -------- h1prev GEMM first: overlaps L0's cell0 --------
            if (t > 0) {
                wait_rel(rel1, (unsigned)t, true);   // inv, then cached h1prev
                hgemm(h1T + (size_t)pprev * HT_ELEMS, &s1.bw[64 * 512]);
            }
            // -------- critical: h0(t) -> gates1 -> cell1 -> publish ---------
            wait_rel(rel0, (unsigned)(t + 1), true); // inv, then cached h0
            if (t > 0 && tid < 8) {     // zero consumed parity slots:
                // safe: rel0>=t+1 => all L0 read mu(t-1); step-t+1 writers
                // are gated behind rel1=t+1 which is after this WG's arrive.
                st_f32(&muacc[(pprev * 128 + g) * 8 + tid], 0.f);
                st_f32(&sgacc[(pprev * 128 + g) * 8 + tid], 0.f);
            }
            hgemm(h0T + (size_t)pcur * HT_ELEMS, &s1.bw[0]);        // h0cur
            reduce_gates(s1.gtb);
            __syncthreads();
            // cell1 + h1 publish + partial atomics
            u16* hw = h1T + (size_t)pcur * HT_ELEMS;
            const int c_ = g >> 1, half = g & 1;
            #pragma unroll
            for (int p = 0; p < 2; ++p) {
                int id = tid + p * NT;
                int b = id >> 3, j = id & 7;
                float gi = s1.gtb[b * 33 + 4 * j + 0] + s1.bias[4 * j + 0];
                float gf = s1.gtb[b * 33 + 4 * j + 1] + s1.bias[4 * j + 1];
                float gg = s1.gtb[b * 33 + 4 * j + 2] + s1.bias[4 * j + 2];
                float go = s1.gtb[b * 33 + 4 * j + 3] + s1.bias[4 * j + 3];
                float cold = (p == 0) ? creg0 : creg1;
                float cn = sigm(gf) * cold + sigm(gi) * tanh_(gg);
                float hn = sigm(go) * tanh_(cn);
                if (p == 0) creg0 = cn; else creg1 = cn;
                unsigned hv = f2bf(hn);
                unsigned other = (unsigned)__shfl_xor((int)hv, 1);
                if ((j & 1) == 0) {
                    int l = half * 32 + (b & 31), mb = b >> 5;
                    st_u32(reinterpret_cast<unsigned*>(hw + ((size_t)(c_ * 4 + mb) * 512 + l * 8 + j)),
                           hv | (other << 16));
                }
                float pmu = hn * s1.mwv[j], psg = hn * s1.swv[j];
                pmu += __shfl_xor(pmu, 1); pmu += __shfl_xor(pmu, 2); pmu += __shfl_xor(pmu, 4);
                psg += __shfl_xor(psg, 1); psg += __shfl_xor(psg, 2); psg += __shfl_xor(psg, 4);
                if (j == 0) {
                    atomicAdd(&muacc[(pcur * 128 + b) * 8 + (g & 7)], pmu);
                    atomicAdd(&sgacc[(pcur * 128 + b) * 8 + (g & 7)], psg);
                }
            }
            arrive_release(f1c, rel1);            // last arriver -> rel1=t+1
        }
    }

    // ---- final output t = T_-1 (parity 1) ----
    if (isL0) {
        wait_rel(rel1, (unsigned)T_, false);      // h1(T-1) partials at LLC
        if (tid == 0) {
            float4 x = ld4f(&muacc[(1 * 128 + g) * 8]);
            float4 y = ld4f(&muacc[(1 * 128 + g) * 8 + 4]);
            float mu = (x.x + x.y) + (x.z + x.w) + (y.x + y.y) + (y.z + y.w) + mub_r;
            float4 z = ld4f(&sgacc[(1 * 128 + g) * 8]);
            float4 u2 = ld4f(&sgacc[(1 * 128 + g) * 8 + 4]);
            float sg = (z.x + z.y) + (z.z + z.w) + (u2.x + u2.y) + (u2.z + u2.w) + sgb_r;
            out[((size_t)g * T_ + (T_ - 1)) * 2 + 0] = mu;
            out[((size_t)g * T_ + (T_ - 1)) * 2 + 1] = softp(sg);
        }
    }
}

// ---------------- host ----------------

extern "C" void kernel_launch(void* const* d_in, const int* in_sizes, int n_in,
                              void* d_out, int out_size, void* d_ws, size_t ws_size,
                              hipStream_t stream) {
    const float* feat = (const float*)d_in[0];
    const float* emb  = (const float*)d_in[1];
    const void*  mask = d_in[2];
    const float* Wih0 = (const float*)d_in[3];
    const float* Whh0 = (const float*)d_in[4];
    const float* bih0 = (const float*)d_in[5];
    const float* bhh0 = (const float*)d_in[6];
    const float* Wih1 = (const float*)d_in[7];
    const float* Whh1 = (const float*)d_in[8];
    const float* bih1 = (const float*)d_in[9];
    const float* bhh1 = (const float*)d_in[10];
    const float* Wtgt = (const float*)d_in[11];
    const float* btgt = (const float*)d_in[12];
    const float* muw  = (const float*)d_in[13];
    const float* mub  = (const float*)d_in[14];
    const float* sgw  = (const float*)d_in[15];
    const float* sgb  = (const float*)d_in[16];
    float* out = (float*)d_out;
    char* ws = (char*)d_ws;
    (void)in_sizes; (void)n_in; (void)out_size; (void)ws_size;

    size_t off = 0;
    auto alloc = [&](size_t bytes) {
        size_t o = off;
        off = (off + bytes + 255) & ~(size_t)255;
        return o;
    };
    size_t o_flags = alloc(256);
    size_t o_actr  = alloc(4 * 32 * 4);   // f0c@0, f1c@32, rel0@64, rel1@96 (u32 idx)
    size_t o_muacc = alloc((size_t)2 * 128 * 8 * 4);
    size_t o_sgacc = alloc((size_t)2 * 128 * 8 * 4);
    size_t zero_end = off;
    size_t o_h0    = alloc((size_t)2 * HT_ELEMS * 2);
    size_t o_h1    = alloc((size_t)2 * HT_ELEMS * 2);
    size_t o_fb2   = alloc((size_t)T_ * 32 * 4 * 512 * 2);

    int*      flags = (int*)(ws + o_flags);
    unsigned* actr  = (unsigned*)(ws + o_actr);
    float*    muacc = (float*)(ws + o_muacc);
    float*    sgacc = (float*)(ws + o_sgacc);
    u16*      h0    = (u16*)(ws + o_h0);
    u16*      h1    = (u16*)(ws + o_h1);
    u16*      fb2   = (u16*)(ws + o_fb2);

    hipMemsetAsync(ws, 0, zero_end, stream);
    detect_mask<<<20, 256, 0, stream>>>((const unsigned*)mask, flags);
    featconv<<<10240, 256, 0, stream>>>(feat, fb2);

    persist<<<NBLK, NT, 0, stream>>>(
        fb2, emb, mask, flags,
        Wih0, Whh0, bih0, bhh0,
        Wih1, Whh1, bih1, bhh1,
        Wtgt, btgt, muw, mub, sgw, sgb,
        h0, h1, muacc, sgacc, actr, out);
}

// Round 15
// 3060.830 us; speedup vs baseline: 1.6290x; 1.0723x over previous
//
#include <hip/hip_runtime.h>

// DeepAR MI355X round 13: split data-arrive / partials-arrive.
// r12 post-mortem: cached h-reads -2.7% => LLC-throughput theory falsified
// (6th falsified theory). Budget: 20.5us/step, MFMA-busy 1.6us, VALU-busy
// 1.8us => ~17us waiting. Unexamined cost: every arrive drains 256
// CONTENDED atomicAdds (16 WGs share each muacc/sgacc slot => 16-deep
// serialized RMW chains at LLC) before raising the flag — in BOTH critical
// phases. This round: h-stores drain+publish rel0/rel1 immediately
// (data-arrive); pmu/psg reduce+atomics deferred after it, drained
// separately, published on rel0b/rel1b (partials-arrive). The only partials
// consumer (L0's mu read) waits rel0b>=t && rel1b>=t — these lag their data
// flags by atomic-ACK time only, overlapped with the other group's phase.
// DAG: L0(t) <- {rel0b,rel1b}>=t; L1(t) <- rel1>=t (own), rel0>=t+1.
// No cycles; t=0 skips; final waits rel0b,rel1b >= T. Zeroing lifetime
// unchanged (drained before f1c arrive; new writers gated behind b-flags).
// Everything else identical to r12 (cached h reads + per-wait acquire-inv,
// arrive-and-release last-arriver publication, reg prefetch, reg labels).
// B=128, T=160, F=512, E=64, H=1024, L=2. Output [B,T,2] fp32.

#define B_   128
#define T_   160
#define FD   512
#define E_   64
#define H_   1024
#define NT   512
#define NBLK 256
#define CH0  100                     // L0 K-chunks (K=1600: 32 feat, 4 lab, 64 h0)
#define CH1  128                     // L1 K-chunks (K=2048: 64 h0cur, 64 h1prev)
#define HT_ELEMS (64 * 4 * 512)      // per-parity h tile elems (= B_*H_)

typedef unsigned short u16;
typedef unsigned long long u64;
typedef __attribute__((ext_vector_type(8))) short bf16x8;
typedef __attribute__((ext_vector_type(16))) float f32x16;

__device__ __forceinline__ bf16x8 ld8(const u16* p) {
    return *reinterpret_cast<const bf16x8*>(p);
}
// small coherent reads (mu/sig partials) — LLC-direct atomics, low volume
__device__ __forceinline__ float4 ld4f(const float* p) {
    u64* q = (u64*)p;
    union { u64 v[2]; float4 f; } u_;
    u_.v[0] = __hip_atomic_load(q + 0, __ATOMIC_RELAXED, __HIP_MEMORY_SCOPE_AGENT);
    u_.v[1] = __hip_atomic_load(q + 1, __ATOMIC_RELAXED, __HIP_MEMORY_SCOPE_AGENT);
    return u_.f;
}
__device__ __forceinline__ f32x16 mfma32(bf16x8 a, bf16x8 b, f32x16 c) {
    return __builtin_amdgcn_mfma_f32_32x32x16_bf16(a, b, c, 0, 0, 0);
}
__device__ __forceinline__ u16 f2bf(float x) {
    unsigned u = __float_as_uint(x);
    u += 0x7FFFu + ((u >> 16) & 1u);   // RNE
    return (u16)(u >> 16);
}
__device__ __forceinline__ float sigm(float x)  { return 1.f / (1.f + __expf(-x)); }
__device__ __forceinline__ float tanh_(float x) { return 1.f - 2.f / (__expf(2.f * x) + 1.f); }
__device__ __forceinline__ float softp(float x) { return x > 20.f ? x : log1pf(__expf(x)); }

__device__ __forceinline__ void st_u32(unsigned* p, unsigned v) {
    __hip_atomic_store(p, v, __ATOMIC_RELAXED, __HIP_MEMORY_SCOPE_AGENT);
}
__device__ __forceinline__ void st_f32(float* p, float v) {
    __hip_atomic_store(p, v, __ATOMIC_RELAXED, __HIP_MEMORY_SCOPE_AGENT);
}

// ---- split-barrier primitives ----

// waiter: poll one release word; if acq, ONE acquire load (L1+L2 inv).
__device__ __forceinline__ void wait_rel(unsigned* rel, unsigned tgt, bool acq) {
    if (threadIdx.x == 0) {
        while (__hip_atomic_load(rel, __ATOMIC_RELAXED, __HIP_MEMORY_SCOPE_AGENT) < tgt)
            __builtin_amdgcn_s_sleep(2);
        if (acq)
            (void)__hip_atomic_load(rel, __ATOMIC_ACQUIRE, __HIP_MEMORY_SCOPE_AGENT);
    }
    __atomic_signal_fence(__ATOMIC_ACQUIRE);   // compiler ordering
    __syncthreads();
}
// wait on two release words (no inv) — used for the partials gates.
__device__ __forceinline__ void wait_two(unsigned* ra, unsigned* rb, unsigned tgt) {
    if (threadIdx.x == 0) {
        while (__hip_atomic_load(ra, __ATOMIC_RELAXED, __HIP_MEMORY_SCOPE_AGENT) < tgt)
            __builtin_amdgcn_s_sleep(2);
        while (__hip_atomic_load(rb, __ATOMIC_RELAXED, __HIP_MEMORY_SCOPE_AGENT) < tgt)
            __builtin_amdgcn_s_sleep(2);
    }
    __atomic_signal_fence(__ATOMIC_ACQUIRE);
    __syncthreads();
}
// arrive: drain this WG's outstanding stores/atomics to LLC, FAA the group
// counter; the 128th arriver of each step publishes the release word.
__device__ __forceinline__ void arrive_release(unsigned* cnt, unsigned* rel) {
    __builtin_amdgcn_s_waitcnt(0);   // this wave's stores/atomics at LLC
    __syncthreads();                 // all waves drained
    if (threadIdx.x == 0) {
        unsigned n = __hip_atomic_fetch_add(cnt, 1u, __ATOMIC_RELAXED,
                                            __HIP_MEMORY_SCOPE_AGENT) + 1u;
        if ((n & 127u) == 0u)        // last arriver: all data provably at LLC
            __hip_atomic_store(rel, n >> 7, __ATOMIC_RELAXED,
                               __HIP_MEMORY_SCOPE_AGENT);
    }
}

// ---------------- prologue kernels ----------------

__global__ void detect_mask(const unsigned* __restrict__ m, int* __restrict__ flags) {
    int i = blockIdx.x * 256 + threadIdx.x;   // exactly 5120 words (20480 bytes)
    unsigned w = m[i];
    if (w > 1u) atomicOr(&flags[0], 1);
    if (w != 0u && w != 0x3F800000u) atomicOr(&flags[1], 1);
}

// feat [B][T][512] fp32 -> fb2 [T][c=32][mblk=4][512] bf16 (MFMA A-frag tiles)
__global__ void featconv(const float* __restrict__ feat, u16* __restrict__ fb2) {
    int i = blockIdx.x * 256 + threadIdx.x;   // [0, 160*16384) float4 units
    int t = i >> 14;
    int u = i & 16383;
    int c = u >> 9;
    int r = u & 511;
    int mm = r >> 7;
    int l  = (r >> 1) & 63;
    int jj = r & 1;
    int b = mm * 32 + (l & 31);
    int k = c * 16 + (l >> 5) * 8 + jj * 4;
    float4 v = reinterpret_cast<const float4*>(feat)[((size_t)b * T_ + t) * 128 + (k >> 2)];
    ushort4 o = make_ushort4(f2bf(v.x), f2bf(v.y), f2bf(v.z), f2bf(v.w));
    reinterpret_cast<ushort4*>(fb2)[((((size_t)t * 32 + c) * 4 + mm) * 512 + l * 8 + jj * 4) >> 2] = o;
}

// ---------------- persistent kernel ----------------

struct SM0 {                       // layer-0 WGs
    u16   bw[CH0 * 512];           // 102400 B, B-frags: bw[ch*512 + lane*8 + j]
    float gtb[4224];               // 16896 B: K-reduce scratch [16][256] / gates [128][33]
    float mu_s[128];
    float uu[32], vv[32], bias[32];
    float mwv[8], swv[8];
    unsigned char msk[128];
};
struct SM1 {                       // layer-1 WGs
    u16   bw[CH1 * 512];           // 131072 B
    float gtb[4224];
    float bias[32];
    float mwv[8], swv[8];
};
union SMU { SM0 a; SM1 b; };

__global__ void __launch_bounds__(NT, 2) persist(
    const u16* __restrict__ fb2, const float* __restrict__ emb,
    const void* __restrict__ mask, const int* __restrict__ flags,
    const float* __restrict__ Wih0, const float* __restrict__ Whh0,
    const float* __restrict__ bih0, const float* __restrict__ bhh0,
    const float* __restrict__ Wih1, const float* __restrict__ Whh1,
    const float* __restrict__ bih1, const float* __restrict__ bhh1,
    const float* __restrict__ Wtgt, const float* __restrict__ btgt,
    const float* __restrict__ muw, const float* __restrict__ mubp,
    const float* __restrict__ sgw, const float* __restrict__ sgbp,
    u16* __restrict__ h0T, u16* __restrict__ h1T,
    float* __restrict__ muacc, float* __restrict__ sgacc,
    unsigned* __restrict__ actr,
    float* __restrict__ out)
{
    __shared__ SMU smu;
    const int tid  = threadIdx.x;
    const int blk  = blockIdx.x;
    const bool isL0 = blk < 128;
    const int g    = isL0 ? blk : blk - 128;   // hidden units g*8..g*8+7
    const int wv   = tid >> 6;
    const int m    = wv & 3;                   // M-tile (rows m*32..m*32+31)
    const int s    = wv >> 2;                  // K-split half
    const int lane = tid & 63;
    const int l31  = lane & 31;

    unsigned* f0c   = actr;              // L0 data-arrival counter
    unsigned* f1c   = actr + 32;         // L1 data-arrival counter
    unsigned* f0b   = actr + 64;         // L0 partials-arrival counter
    unsigned* f1b   = actr + 96;         // L1 partials-arrival counter
    unsigned* rel0  = actr + 128;        // h0 data ready
    unsigned* rel1  = actr + 160;        // h1 data ready
    unsigned* rel0b = actr + 192;        // L0 partials ready
    unsigned* rel1b = actr + 224;        // L1 partials ready

    const float mub_r = mubp[0], sgb_r = sgbp[0];

    // ---- one-time init: pack weights into MFMA B-frag layout in LDS ----
    if (isL0) {
        SM0& s0 = smu.a;
        for (int i = tid; i < CH0 * 512; i += NT) {
            int ch = i >> 9, r = i & 511, l = r >> 3, jj = r & 7;
            int pc = l & 31;
            int kk = ch * 16 + (l >> 5) * 8 + jj;
            int q = pc & 3, j = pc >> 2;
            int row = q * H_ + g * 8 + j;
            float v = (kk < 576) ? Wih0[row * 576 + kk]
                                 : Whh0[(size_t)row * H_ + (kk - 576)];
            s0.bw[i] = f2bf(v);
        }
        if (tid < 32) {
            int pc = tid, q = pc & 3, j = pc >> 2;
            int row = q * H_ + g * 8 + j;
            s0.bias[pc] = bih0[row] + bhh0[row];
            float su = 0.f, sv = 0.f;
            for (int e = 0; e < 64; ++e) {       // rank-1 label vectors
                float wl = Wih0[row * 576 + 512 + e];
                su += Wtgt[e] * wl;
                sv += btgt[e] * wl;
            }
            s0.uu[pc] = su; s0.vv[pc] = sv;
        }
        if (tid < 8) {
            int h = g * 8 + tid;
            s0.mwv[tid] = muw[2 * h]; s0.swv[tid] = sgw[2 * h];
        }
    } else {
        SM1& s1 = smu.b;
        for (int i = tid; i < CH1 * 512; i += NT) {
            int ch = i >> 9, r = i & 511, l = r >> 3, jj = r & 7;
            int pc = l & 31;
            int kk = ch * 16 + (l >> 5) * 8 + jj;
            int q = pc & 3, j = pc >> 2;
            int row = q * H_ + g * 8 + j;
            float v = (kk < 1024) ? Wih1[(size_t)row * H_ + kk]
                                  : Whh1[(size_t)row * H_ + (kk - 1024)];
            s1.bw[i] = f2bf(v);
        }
        if (tid < 32) {
            int pc = tid, q = pc & 3, j = pc >> 2;
            int row = q * H_ + g * 8 + j;
            s1.bias[pc] = bih1[row] + bhh1[row];
        }
        if (tid < 8) {
            int h = g * 8 + tid;
            s1.mwv[tid] = muw[2 * h + 1]; s1.swv[tid] = sgw[2 * h + 1];
        }
    }
    const int nonbin = flags[0], nonfl = flags[1];
    __syncthreads();

    float creg0 = 0.f, creg1 = 0.f;
    f32x16 acc;
    #pragma unroll
    for (int r = 0; r < 16; ++r) acc[r] = 0.f;

    // K-split reduce: acc (both halves) -> gates in gtb[128][33]; zeroes acc.
    auto reduce_gates = [&](float* g_) {
        if (s == 1) {
            #pragma unroll
            for (int r = 0; r < 16; ++r) g_[r * 256 + m * 64 + lane] = acc[r];
        }
        __syncthreads();
        f32x16 tot;
        if (s == 0) {
            #pragma unroll
            for (int r = 0; r < 16; ++r) tot[r] = acc[r] + g_[r * 256 + m * 64 + lane];
        }
        __syncthreads();
        if (s == 0) {
            #pragma unroll
            for (int r = 0; r < 16; ++r) {
                int row = m * 32 + (r & 3) + 8 * (r >> 2) + 4 * (lane >> 5);
                g_[row * 33 + l31] = tot[r];
            }
        }
        #pragma unroll
        for (int r = 0; r < 16; ++r) acc[r] = 0.f;
    };

    // 32-chunk h-GEMM, PLAIN cached loads (L2-shared across the XCD's WGs),
    // full-depth register prefetch retained.
    auto hgemm = [&](const u16* hp, const u16* bwb) {
        bf16x8 areg[32];
        #pragma unroll
        for (int c = 0; c < 32; ++c) {
            int ch = s * 32 + c;
            areg[c] = ld8(hp + ((size_t)ch * 4 + m) * 512 + lane * 8);
        }
        #pragma unroll
        for (int c = 0; c < 32; ++c) {
            int ch = s * 32 + c;
            bf16x8 b = *(const bf16x8*)&bwb[ch * 512 + lane * 8];
            acc = mfma32(areg[c], b, acc);
        }
    };

    // feat+label GEMM for step t1 (chunks 0..35, s-split 18 each).
    auto featlab = [&](int t1, bool use_mask) {
        SM0& s0 = smu.a;
        const int bq = m * 32 + l31;
        bool um = false;
        if (use_mask && s == 1) {
            int mi = bq * T_ + t1;
            um = !nonbin ? (reinterpret_cast<const int*>(mask)[mi] != 0)
               : !nonfl  ? (reinterpret_cast<const float*>(mask)[mi] != 0.f)
                         : (reinterpret_cast<const unsigned char*>(mask)[mi] != 0);
        }
        #pragma unroll 6
        for (int c = 0; c < 18; ++c) {
            int ch = s * 18 + c;
            bf16x8 a;
            if (ch < 32) {
                a = ld8(fb2 + (((size_t)t1 * 32 + ch) * 4 + m) * 512 + lane * 8);
            } else {
                const float* ep = &emb[((size_t)bq * T_ + t1) * 64
                                       + (ch - 32) * 16 + (lane >> 5) * 8];
                float4 v0 = *reinterpret_cast<const float4*>(ep);
                float4 v1 = *reinterpret_cast<const float4*>(ep + 4);
                if (um) { v0.x=v0.y=v0.z=v0.w=0.f; v1.x=v1.y=v1.z=v1.w=0.f; }
                a[0] = (short)f2bf(v0.x); a[1] = (short)f2bf(v0.y);
                a[2] = (short)f2bf(v0.z); a[3] = (short)f2bf(v0.w);
                a[4] = (short)f2bf(v1.x); a[5] = (short)f2bf(v1.y);
                a[6] = (short)f2bf(v1.z); a[7] = (short)f2bf(v1.w);
            }
            bf16x8 b = *(const bf16x8*)&s0.bw[ch * 512 + lane * 8];
            acc = mfma32(a, b, acc);
        }
    };

    // pre-loop: gates0(0) = feat(0)+lab(0) GEMM, reduced into gtb
    if (isL0) {
        featlab(0, false);
        reduce_gates(smu.a.gtb);
    }

    for (int t = 0; t < T_; ++t) {
        const int pcur = t & 1, pprev = pcur ^ 1;

        if (isL0) {
            SM0& s0 = smu.a;
            // ---- critical: partials(t-1) -> mu -> cell0 -> publish h0 ----
            if (t > 0) {
                wait_two(rel0b, rel1b, (unsigned)t);   // all mu(t-1) atomics
                if (tid < 128) {
                    float4 x = ld4f(&muacc[(pprev * 128 + tid) * 8]);
                    float4 y = ld4f(&muacc[(pprev * 128 + tid) * 8 + 4]);
                    s0.mu_s[tid] = (x.x + x.y) + (x.z + x.w) + (y.x + y.y) + (y.z + y.w) + mub_r;
                    int mi = tid * T_ + t;
                    bool um = !nonbin ? (reinterpret_cast<const int*>(mask)[mi] != 0)
                            : !nonfl  ? (reinterpret_cast<const float*>(mask)[mi] != 0.f)
                                      : (reinterpret_cast<const unsigned char*>(mask)[mi] != 0);
                    s0.msk[tid] = um ? 1 : 0;
                }
            }
            __syncthreads();
            if (t > 0 && tid == 0) {
                float4 x = ld4f(&sgacc[(pprev * 128 + g) * 8]);
                float4 y = ld4f(&sgacc[(pprev * 128 + g) * 8 + 4]);
                float sg = (x.x + x.y) + (x.z + x.w) + (y.x + y.y) + (y.z + y.w) + sgb_r;
                out[((size_t)g * T_ + (t - 1)) * 2 + 0] = s0.mu_s[g];
                out[((size_t)g * T_ + (t - 1)) * 2 + 1] = softp(sg);
            }
            // cell0: compute + h0 stores ONLY (partials deferred)
            float hn_st0 = 0.f, hn_st1 = 0.f;
            u16* hw = h0T + (size_t)pcur * HT_ELEMS;
            const int c_ = g >> 1, half = g & 1;
            #pragma unroll
            for (int p = 0; p < 2; ++p) {
                int id = tid + p * NT;
                int b = id >> 3, j = id & 7;
                float gi = s0.gtb[b * 33 + 4 * j + 0] + s0.bias[4 * j + 0];
                float gf = s0.gtb[b * 33 + 4 * j + 1] + s0.bias[4 * j + 1];
                float gg = s0.gtb[b * 33 + 4 * j + 2] + s0.bias[4 * j + 2];
                float go = s0.gtb[b * 33 + 4 * j + 3] + s0.bias[4 * j + 3];
                if (t > 0 && s0.msk[b]) {       // rank-1 mu-label term
                    float mu = s0.mu_s[b];
                    gi += mu * s0.uu[4 * j + 0] + s0.vv[4 * j + 0];
                    gf += mu * s0.uu[4 * j + 1] + s0.vv[4 * j + 1];
                    gg += mu * s0.uu[4 * j + 2] + s0.vv[4 * j + 2];
                    go += mu * s0.uu[4 * j + 3] + s0.vv[4 * j + 3];
                }
                float cold = (p == 0) ? creg0 : creg1;
                float cn = sigm(gf) * cold + sigm(gi) * tanh_(gg);
                float hn = sigm(go) * tanh_(cn);
                if (p == 0) { creg0 = cn; hn_st0 = hn; }
                else        { creg1 = cn; hn_st1 = hn; }
                unsigned hv = f2bf(hn);
                unsigned other = (unsigned)__shfl_xor((int)hv, 1);
                if ((j & 1) == 0) {
                    int l = half * 32 + (b & 31), mb = b >> 5;
                    st_u32(reinterpret_cast<unsigned*>(hw + ((size_t)(c_ * 4 + mb) * 512 + l * 8 + j)),
                           hv | (other << 16));
                }
            }
            arrive_release(f0c, rel0);            // h0(t) data at LLC -> rel0

            // ---- partials (off data-critical path): reduce + atomics ----
            #pragma unroll
            for (int p = 0; p < 2; ++p) {
                int id = tid + p * NT;
                int b = id >> 3, j = id & 7;
                float hn = (p == 0) ? hn_st0 : hn_st1;
                float pmu = hn * s0.mwv[j], psg = hn * s0.swv[j];
                pmu += __shfl_xor(pmu, 1); pmu += __shfl_xor(pmu, 2); pmu += __shfl_xor(pmu, 4);
                psg += __shfl_xor(psg, 1); psg += __shfl_xor(psg, 2); psg += __shfl_xor(psg, 4);
                if (j == 0) {
                    atomicAdd(&muacc[(pcur * 128 + b) * 8 + (g & 7)], pmu);
                    atomicAdd(&sgacc[(pcur * 128 + b) * 8 + (g & 7)], psg);
                }
            }
            arrive_release(f0b, rel0b);           // L0 partials at LLC -> rel0b

            // ---- off-critical: gates0(t+1), overlaps L1's chain ----
            if (t + 1 < T_) {
                wait_rel(rel0, (unsigned)(t + 1), true);  // inv, then cached h0
                hgemm(h0T + (size_t)pcur * HT_ELEMS, &s0.bw[36 * 512]);
                featlab(t + 1, true);
                reduce_gates(s0.gtb);
            }
        } else {
            SM1& s1 = smu.b;
            // ---- h1prev GEMM first: overlaps L0's cell0 ----
            if (t > 0) {
                wait_rel(rel1, (unsigned)t, true);   // inv, then cached h1prev
                hgemm(h1T + (size_t)pprev * HT_ELEMS, &s1.bw[64 * 512]);
            }
            // ---- critical: h0(t) -> gates1 -> cell1 -> publish ----
            wait_rel(rel0, (unsigned)(t + 1), true); // inv, then cached h0
            if (t > 0 && tid < 8) {     // zero consumed parity slots:
                // safe: rel0>=t+1 => all L0 read mu(t-1); step-t+1 writers
                // are gated behind rel0b/rel1b=t+1, both after this drain.
                st_f32(&muacc[(pprev * 128 + g) * 8 + tid], 0.f);
                st_f32(&sgacc[(pprev * 128 + g) * 8 + tid], 0.f);
            }
            hgemm(h0T + (size_t)pcur * HT_ELEMS, &s1.bw[0]);        // h0cur
            reduce_gates(s1.gtb);
            __syncthreads();
            // cell1: compute + h1 stores ONLY (partials deferred)
            float hn_st0 = 0.f, hn_st1 = 0.f;
            u16* hw = h1T + (size_t)pcur * HT_ELEMS;
            const int c_ = g >> 1, half = g & 1;
            #pragma unroll
            for (int p = 0; p < 2; ++p) {
                int id = tid + p * NT;
                int b = id >> 3, j = id & 7;
                float gi = s1.gtb[b * 33 + 4 * j + 0] + s1.bias[4 * j + 0];
                float gf = s1.gtb[b * 33 + 4 * j + 1] + s1.bias[4 * j + 1];
                float gg = s1.gtb[b * 33 + 4 * j + 2] + s1.bias[4 * j + 2];
                float go = s1.gtb[b * 33 + 4 * j + 3] + s1.bias[4 * j + 3];
                float cold = (p == 0) ? creg0 : creg1;
                float cn = sigm(gf) * cold + sigm(gi) * tanh_(gg);
                float hn = sigm(go) * tanh_(cn);
                if (p == 0) { creg0 = cn; hn_st0 = hn; }
                else        { creg1 = cn; hn_st1 = hn; }
                unsigned hv = f2bf(hn);
                unsigned other = (unsigned)__shfl_xor((int)hv, 1);
                if ((j & 1) == 0) {
                    int l = half * 32 + (b & 31), mb = b >> 5;
                    st_u32(reinterpret_cast<unsigned*>(hw + ((size_t)(c_ * 4 + mb) * 512 + l * 8 + j)),
                           hv | (other << 16));
                }
            }
            arrive_release(f1c, rel1);            // h1(t) data at LLC -> rel1

            // ---- partials (off data-critical path): reduce + atomics ----
            #pragma unroll
            for (int p = 0; p < 2; ++p) {
                int id = tid + p * NT;
                int b = id >> 3, j = id & 7;
                float hn = (p == 0) ? hn_st0 : hn_st1;
                float pmu = hn * s1.mwv[j], psg = hn * s1.swv[j];
                pmu += __shfl_xor(pmu, 1); pmu += __shfl_xor(pmu, 2); pmu += __shfl_xor(pmu, 4);
                psg += __shfl_xor(psg, 1); psg += __shfl_xor(psg, 2); psg += __shfl_xor(psg, 4);
                if (j == 0) {
                    atomicAdd(&muacc[(pcur * 128 + b) * 8 + (g & 7)], pmu);
                    atomicAdd(&sgacc[(pcur * 128 + b) * 8 + (g & 7)], psg);
                }
            }
            arrive_release(f1b, rel1b);           // L1 partials at LLC -> rel1b
        }
    }

    // ---- final output t = T_-1 (parity 1) ----
    if (isL0) {
        wait_two(rel0b, rel1b, (unsigned)T_);     // all partials at LLC
        if (tid == 0) {
            float4 x = ld4f(&muacc[(1 * 128 + g) * 8]);
            float4 y = ld4f(&muacc[(1 * 128 + g) * 8 + 4]);
            float mu = (x.x + x.y) + (x.z + x.w) + (y.x + y.y) + (y.z + y.w) + mub_r;
            float4 z = ld4f(&sgacc[(1 * 128 + g) * 8]);
            float4 u2 = ld4f(&sgacc[(1 * 128 + g) * 8 + 4]);
            float sg = (z.x + z.y) + (z.z + z.w) + (u2.x + u2.y) + (u2.z + u2.w) + sgb_r;
            out[((size_t)g * T_ + (T_ - 1)) * 2 + 0] = mu;
            out[((size_t)g * T_ + (T_ - 1)) * 2 + 1] = softp(sg);
        }
    }
}

// ---------------- host ----------------

extern "C" void kernel_launch(void* const* d_in, const int* in_sizes, int n_in,
                              void* d_out, int out_size, void* d_ws, size_t ws_size,
                              hipStream_t stream) {
    const float* feat = (const float*)d_in[0];
    const float* emb  = (const float*)d_in[1];
    const void*  mask = d_in[2];
    const float* Wih0 = (const float*)d_in[3];
    const float* Whh0 = (const float*)d_in[4];
    const float* bih0 = (const float*)d_in[5];
    const float* bhh0 = (const float*)d_in[6];
    const float* Wih1 = (const float*)d_in[7];
    const float* Whh1 = (const float*)d_in[8];
    const float* bih1 = (const float*)d_in[9];
    const float* bhh1 = (const float*)d_in[10];
    const float* Wtgt = (const float*)d_in[11];
    const float* btgt = (const float*)d_in[12];
    const float* muw  = (const float*)d_in[13];
    const float* mub  = (const float*)d_in[14];
    const float* sgw  = (const float*)d_in[15];
    const float* sgb  = (const float*)d_in[16];
    float* out = (float*)d_out;
    char* ws = (char*)d_ws;
    (void)in_sizes; (void)n_in; (void)out_size; (void)ws_size;

    size_t off = 0;
    auto alloc = [&](size_t bytes) {
        size_t o = off;
        off = (off + bytes + 255) & ~(size_t)255;
        return o;
    };
    size_t o_flags = alloc(256);
    size_t o_actr  = alloc(8 * 32 * 4);   // f0c,f1c,f0b,f1b,rel0,rel1,rel0b,rel1b
    size_t o_muacc = alloc((size_t)2 * 128 * 8 * 4);
    size_t o_sgacc = alloc((size_t)2 * 128 * 8 * 4);
    size_t zero_end = off;
    size_t o_h0    = alloc((size_t)2 * HT_ELEMS * 2);
    size_t o_h1    = alloc((size_t)2 * HT_ELEMS * 2);
    size_t o_fb2   = alloc((size_t)T_ * 32 * 4 * 512 * 2);

    int*      flags = (int*)(ws + o_flags);
    unsigned* actr  = (unsigned*)(ws + o_actr);
    float*    muacc = (float*)(ws + o_muacc);
    float*    sgacc = (float*)(ws + o_sgacc);
    u16*      h0    = (u16*)(ws + o_h0);
    u16*      h1    = (u16*)(ws + o_h1);
    u16*      fb2   = (u16*)(ws + o_fb2);

    hipMemsetAsync(ws, 0, zero_end, stream);
    detect_mask<<<20, 256, 0, stream>>>((const unsigned*)mask, flags);
    featconv<<<10240, 256, 0, stream>>>(feat, fb2);

    persist<<<NBLK, NT, 0, stream>>>(
        fb2, emb, mask, flags,
        Wih0, Whh0, bih0, bhh0,
        Wih1, Whh1, bih1, bhh1,
        Wtgt, btgt, muw, mub, sgw, sgb,
        h0, h1, muacc, sgacc, actr, out);
}